// Round 5
// baseline (1380.831 us; speedup 1.0000x reference)
//
#include <hip/hip_runtime.h>

static constexpr int N_ = 40000;
static constexpr int E_ = 1280000;
static constexpr int NS = N_ * 64;      // 2,560,000 scalar elems
static constexpr int NV = N_ * 48;      // 1,920,000 vector elems

__device__ __forceinline__ float silu_f(float x) { return __fdividef(x, 1.f + __expf(-x)); }

// ---- per-node attention precompute ----
// P1[n][j] = ba1[j] + sum_k s[n][k]*Wa1[k][j]      (s_i / dst part)
// P2[n][j] =          sum_k s[n][k]*Wa1[64+k][j]   (s_j / src part)
__global__ void k_precompute(const float* __restrict__ scalars, const float* __restrict__ Wa1,
                             const float* __restrict__ ba1,
                             float* __restrict__ P1, float* __restrict__ P2)
{
    int t = blockIdx.x * 256 + threadIdx.x;  // t < N*64
    int n = t >> 6, j = t & 63;
    float a1 = ba1[j];
    float a2 = 0.f;
    const float* srow = scalars + (size_t)n * 64;
#pragma unroll 8
    for (int k = 0; k < 64; k++) {
        float s = srow[k];
        a1 = fmaf(s, Wa1[k * 64 + j], a1);
        a2 = fmaf(s, Wa1[(64 + k) * 64 + j], a2);
    }
    P1[t] = a1;
    P2[t] = a2;
}

// ================= CSR build (round-3 proven versions) =================
__global__ void k_hist(const int* __restrict__ eidx, int* __restrict__ cnt)
{
    int e = blockIdx.x * 256 + threadIdx.x;
    atomicAdd(&cnt[eidx[E_ + e]], 1);
}

__global__ void k_scan(const int* __restrict__ cnt, int* __restrict__ row_start)
{
    __shared__ int buf[1024];
    __shared__ int carry;
    int tid = threadIdx.x;
    if (tid == 0) carry = 0;
    __syncthreads();
    for (int c = 0; c < 40; ++c) {   // 40*1024 = 40960 >= N_
        int idx = c * 1024 + tid;
        int v = (idx < N_) ? cnt[idx] : 0;
        buf[tid] = v;
        __syncthreads();
        for (int off = 1; off < 1024; off <<= 1) {
            int t = (tid >= off) ? buf[tid - off] : 0;
            __syncthreads();
            buf[tid] += t;
            __syncthreads();
        }
        if (idx < N_) row_start[idx] = carry + buf[tid] - v;  // exclusive
        __syncthreads();
        if (tid == 1023) carry += buf[1023];
        __syncthreads();
    }
    if (tid == 0) row_start[N_] = carry;  // == E_
}

__global__ void k_scatter(const int* __restrict__ eidx, const int* __restrict__ row_start,
                          int* __restrict__ c2, int* __restrict__ perm)
{
    int e = blockIdx.x * 256 + threadIdx.x;
    int dst = eidx[E_ + e];
    int pos = row_start[dst] + atomicAdd(&c2[dst], 1);
    perm[pos] = e;
}

// ================= edge phase (round-3 proven) =================
__global__ __launch_bounds__(256, 2) void k_edges_sorted(
    const float* __restrict__ edge_vec, const int* __restrict__ eidx,
    const int* __restrict__ perm,
    const float* __restrict__ P1, const float* __restrict__ P2,
    const float* __restrict__ W1, const float* __restrict__ b1,
    const float* __restrict__ Wa1, const float* __restrict__ Wa2,
    const float* __restrict__ ba2,
    float4* __restrict__ attsh, int* __restrict__ srcbuf, float* __restrict__ hbuf)
{
    int i = blockIdx.x * 256 + threadIdx.x;
    int e = perm[i];
    int src = eidx[e];
    int dst = eidx[E_ + e];

    float ev0 = edge_vec[3 * e + 0];
    float ev1 = edge_vec[3 * e + 1];
    float ev2 = edge_vec[3 * e + 2];
    float d = sqrtf(fmaf(ev0, ev0, fmaf(ev1, ev1, ev2 * ev2)));
    float inv_d = __fdividef(1.f, fmaxf(d, 1e-8f));
    float cut = (d < 10.f) ? 0.5f * (__cosf(0.31415927f * d) + 1.f) : 0.f;
    float cutd = cut * inv_d;
    float sh0 = ev1 * inv_d, sh1 = ev2 * inv_d, sh2 = ev0 * inv_d;  // [uy, uz, ux]

    float g[96];
#pragma unroll
    for (int j = 0; j < 96; j++) g[j] = 0.f;
    for (int k = 0; k < 32; k++) {
        float rk = __sinf((float)(k + 1) * 0.31415927f * d) * cutd;
        const float* wa = Wa1 + (128 + k) * 64;
        const float* w1 = W1 + k * 32;
#pragma unroll
        for (int j = 0; j < 64; j++) g[j] = fmaf(rk, wa[j], g[j]);
#pragma unroll
        for (int j = 0; j < 32; j++) g[64 + j] = fmaf(rk, w1[j], g[64 + j]);
    }

    const float* p1 = P1 + (size_t)dst * 64;
    const float* p2 = P2 + (size_t)src * 64;
    float logit = ba2[0];
#pragma unroll
    for (int j = 0; j < 64; j++) {
        float aj = p1[j] + p2[j] + g[j];
        logit = fmaf(silu_f(aj), Wa2[j], logit);
    }
    float att = __fdividef(1.f, 1.f + __expf(-logit));

    float* hrow = hbuf + (size_t)i * 32;
#pragma unroll
    for (int k = 0; k < 32; k++) hrow[k] = silu_f(g[64 + k] + b1[k]);

    attsh[i] = make_float4(att, sh0, sh1, sh2);
    srcbuf[i] = src;
}

// ================= gather: ONLY change vs round 3 — multi-edge ILP + float4 h loads =================
// Block = 256 threads = 4 waves = 2 nodes; even wave: scalar feats (4-edge unroll),
// odd wave: vector feats (2-edge unroll, keeps VGPR under the 4-wave cap).
__global__ __launch_bounds__(256, 4) void k_gather(
    const float* __restrict__ scalars, const float* __restrict__ vectors,
    const float* __restrict__ W2, const float* __restrict__ b2,
    const int* __restrict__ row_start,
    const float4* __restrict__ attsh, const int* __restrict__ srcbuf,
    const float* __restrict__ hbuf,
    float* __restrict__ out)
{
    int wid  = threadIdx.x >> 6;
    int lane = threadIdx.x & 63;
    int n    = blockIdx.x * 2 + (wid >> 1);
    int role = wid & 1;
    int rs = row_start[n];
    int re = row_start[n + 1];

    if (role == 0) {
        float wj[32];
#pragma unroll
        for (int k = 0; k < 32; k++) wj[k] = W2[k * 96 + lane];
        float bj = b2[lane];
        float acc = 0.f;
        int i = rs;
        for (; i + 4 <= re; i += 4) {
            float4 as0 = attsh[i + 0], as1 = attsh[i + 1];
            float4 as2 = attsh[i + 2], as3 = attsh[i + 3];
            int s0 = srcbuf[i + 0], s1 = srcbuf[i + 1];
            int s2 = srcbuf[i + 2], s3 = srcbuf[i + 3];
            float g0 = scalars[(size_t)s0 * 64 + lane];
            float g1 = scalars[(size_t)s1 * 64 + lane];
            float g2 = scalars[(size_t)s2 * 64 + lane];
            float g3 = scalars[(size_t)s3 * 64 + lane];
            const float4* h0 = (const float4*)(hbuf + (size_t)(i + 0) * 32);
            const float4* h1 = (const float4*)(hbuf + (size_t)(i + 1) * 32);
            const float4* h2 = (const float4*)(hbuf + (size_t)(i + 2) * 32);
            const float4* h3 = (const float4*)(hbuf + (size_t)(i + 3) * 32);
            float f0 = bj, f1 = bj, f2 = bj, f3 = bj;
#pragma unroll
            for (int q = 0; q < 8; q++) {
                float4 a0 = h0[q], a1 = h1[q], a2 = h2[q], a3 = h3[q];
                f0 = fmaf(a0.x, wj[4*q+0], f0); f0 = fmaf(a0.y, wj[4*q+1], f0);
                f0 = fmaf(a0.z, wj[4*q+2], f0); f0 = fmaf(a0.w, wj[4*q+3], f0);
                f1 = fmaf(a1.x, wj[4*q+0], f1); f1 = fmaf(a1.y, wj[4*q+1], f1);
                f1 = fmaf(a1.z, wj[4*q+2], f1); f1 = fmaf(a1.w, wj[4*q+3], f1);
                f2 = fmaf(a2.x, wj[4*q+0], f2); f2 = fmaf(a2.y, wj[4*q+1], f2);
                f2 = fmaf(a2.z, wj[4*q+2], f2); f2 = fmaf(a2.w, wj[4*q+3], f2);
                f3 = fmaf(a3.x, wj[4*q+0], f3); f3 = fmaf(a3.y, wj[4*q+1], f3);
                f3 = fmaf(a3.z, wj[4*q+2], f3); f3 = fmaf(a3.w, wj[4*q+3], f3);
            }
            acc = fmaf(as0.x * g0, f0, acc);
            acc = fmaf(as1.x * g1, f1, acc);
            acc = fmaf(as2.x * g2, f2, acc);
            acc = fmaf(as3.x * g3, f3, acc);
        }
        for (; i < re; i++) {
            float4 as = attsh[i];
            int s0 = srcbuf[i];
            const float4* h0 = (const float4*)(hbuf + (size_t)i * 32);
            float f = bj;
#pragma unroll
            for (int q = 0; q < 8; q++) {
                float4 a = h0[q];
                f = fmaf(a.x, wj[4*q+0], f); f = fmaf(a.y, wj[4*q+1], f);
                f = fmaf(a.z, wj[4*q+2], f); f = fmaf(a.w, wj[4*q+3], f);
            }
            acc = fmaf(as.x * scalars[(size_t)s0 * 64 + lane], f, acc);
        }
        out[(size_t)n * 64 + lane] = scalars[(size_t)n * 64 + lane] + acc;
    } else if (lane < 48) {
        int m = lane / 3;
        int c = lane - 3 * m;
        float wf[32], wg[32];
#pragma unroll
        for (int k = 0; k < 32; k++) {
            wf[k] = W2[k * 96 + 64 + m];
            wg[k] = W2[k * 96 + 80 + m];
        }
        float bf = b2[64 + m], bg = b2[80 + m];
        float acc = 0.f;
        int i = rs;
        for (; i + 2 <= re; i += 2) {
            float4 as0 = attsh[i + 0], as1 = attsh[i + 1];
            int s0 = srcbuf[i + 0], s1 = srcbuf[i + 1];
            float vj0 = vectors[(size_t)s0 * 48 + lane];
            float vj1 = vectors[(size_t)s1 * 48 + lane];
            const float4* h0 = (const float4*)(hbuf + (size_t)(i + 0) * 32);
            const float4* h1 = (const float4*)(hbuf + (size_t)(i + 1) * 32);
            float vf0 = bf, vg0 = bg, vf1 = bf, vg1 = bg;
#pragma unroll
            for (int q = 0; q < 8; q++) {
                float4 a0 = h0[q], a1 = h1[q];
                vf0 = fmaf(a0.x, wf[4*q+0], vf0); vg0 = fmaf(a0.x, wg[4*q+0], vg0);
                vf0 = fmaf(a0.y, wf[4*q+1], vf0); vg0 = fmaf(a0.y, wg[4*q+1], vg0);
                vf0 = fmaf(a0.z, wf[4*q+2], vf0); vg0 = fmaf(a0.z, wg[4*q+2], vg0);
                vf0 = fmaf(a0.w, wf[4*q+3], vf0); vg0 = fmaf(a0.w, wg[4*q+3], vg0);
                vf1 = fmaf(a1.x, wf[4*q+0], vf1); vg1 = fmaf(a1.x, wg[4*q+0], vg1);
                vf1 = fmaf(a1.y, wf[4*q+1], vf1); vg1 = fmaf(a1.y, wg[4*q+1], vg1);
                vf1 = fmaf(a1.z, wf[4*q+2], vf1); vg1 = fmaf(a1.z, wg[4*q+2], vg1);
                vf1 = fmaf(a1.w, wf[4*q+3], vf1); vg1 = fmaf(a1.w, wg[4*q+3], vg1);
            }
            float sh0c = (c == 0) ? as0.y : ((c == 1) ? as0.z : as0.w);
            float sh1c = (c == 0) ? as1.y : ((c == 1) ? as1.z : as1.w);
            acc = fmaf(as0.x, fmaf(vj0, vf0, vg0 * sh0c), acc);
            acc = fmaf(as1.x, fmaf(vj1, vf1, vg1 * sh1c), acc);
        }
        for (; i < re; i++) {
            float4 as = attsh[i];
            int s0 = srcbuf[i];
            float vjc = vectors[(size_t)s0 * 48 + lane];
            const float4* h0 = (const float4*)(hbuf + (size_t)i * 32);
            float vf = bf, vg = bg;
#pragma unroll
            for (int q = 0; q < 8; q++) {
                float4 a = h0[q];
                vf = fmaf(a.x, wf[4*q+0], vf); vg = fmaf(a.x, wg[4*q+0], vg);
                vf = fmaf(a.y, wf[4*q+1], vf); vg = fmaf(a.y, wg[4*q+1], vg);
                vf = fmaf(a.z, wf[4*q+2], vf); vg = fmaf(a.z, wg[4*q+2], vg);
                vf = fmaf(a.w, wf[4*q+3], vf); vg = fmaf(a.w, wg[4*q+3], vg);
            }
            float shc = (c == 0) ? as.y : ((c == 1) ? as.z : as.w);
            acc = fmaf(as.x, fmaf(vjc, vf, vg * shc), acc);
        }
        out[NS + (size_t)n * 48 + lane] = vectors[(size_t)n * 48 + lane] + acc;
    }
}

extern "C" void kernel_launch(void* const* d_in, const int* in_sizes, int n_in,
                              void* d_out, int out_size, void* d_ws, size_t ws_size,
                              hipStream_t stream)
{
    const float* scalars  = (const float*)d_in[0];
    const float* vectors  = (const float*)d_in[1];
    const float* edge_vec = (const float*)d_in[2];
    const float* W1  = (const float*)d_in[3];
    const float* b1  = (const float*)d_in[4];
    const float* W2  = (const float*)d_in[5];
    const float* b2  = (const float*)d_in[6];
    const float* Wa1 = (const float*)d_in[7];
    const float* ba1 = (const float*)d_in[8];
    const float* Wa2 = (const float*)d_in[9];
    const float* ba2 = (const float*)d_in[10];
    const int* eidx  = (const int*)d_in[11];

    char* wsb = (char*)d_ws;
    // round-3 proven layout: attsh | P1 | P2 | hbuf | cnt | c2 | row_start | perm | srcbuf
    float4* attsh = (float4*)wsb;                       // E float4      = 20.48 MB
    float*  P1    = (float*)(wsb + (size_t)E_ * 16);    // NS floats     = 10.24 MB
    float*  P2    = P1 + NS;                            // NS floats     = 10.24 MB
    float*  hbuf  = P2 + NS;                            // 32E floats    = 163.84 MB
    int* cnt       = (int*)(hbuf + (size_t)32 * E_);    // N
    int* c2        = cnt + N_;                          // N
    int* row_start = c2 + N_;                           // N+1
    int* perm      = row_start + N_ + 1;                // E
    int* srcbuf    = perm + E_;                         // E  (end ~215.6 MB; round 3 proved ws fits)

    hipMemsetAsync(cnt, 0, (size_t)2 * N_ * sizeof(int), stream);   // cnt + c2
    k_hist<<<5000, 256, 0, stream>>>(eidx, cnt);
    k_scan<<<1, 1024, 0, stream>>>(cnt, row_start);
    k_scatter<<<5000, 256, 0, stream>>>(eidx, row_start, c2, perm);
    k_precompute<<<10000, 256, 0, stream>>>(scalars, Wa1, ba1, P1, P2);
    k_edges_sorted<<<5000, 256, 0, stream>>>(edge_vec, eidx, perm, P1, P2,
                                             W1, b1, Wa1, Wa2, ba2,
                                             attsh, srcbuf, hbuf);
    k_gather<<<20000, 256, 0, stream>>>(scalars, vectors, W2, b2, row_start,
                                        attsh, srcbuf, hbuf, (float*)d_out);
}

// Round 6
// 848.924 us; speedup vs baseline: 1.6266x; 1.6266x over previous
//
#include <hip/hip_runtime.h>

static constexpr int N_ = 40000;
static constexpr int E_ = 1280000;
static constexpr int NS = N_ * 64;      // 2,560,000 scalar elems
static constexpr int NV = N_ * 48;      // 1,920,000 vector elems

__device__ __forceinline__ float silu_f(float x) { return __fdividef(x, 1.f + __expf(-x)); }
__device__ __forceinline__ int rfl(int x) { return __builtin_amdgcn_readfirstlane(x); }

// ---- per-node attention precompute ----
// P1[n][j] = ba1[j] + sum_k s[n][k]*Wa1[k][j]      (s_i / dst part)
// P2[n][j] =          sum_k s[n][k]*Wa1[64+k][j]   (s_j / src part)
__global__ void k_precompute(const float* __restrict__ scalars, const float* __restrict__ Wa1,
                             const float* __restrict__ ba1,
                             float* __restrict__ P1, float* __restrict__ P2)
{
    int t = blockIdx.x * 256 + threadIdx.x;  // t < N*64
    int n = t >> 6, j = t & 63;
    float a1 = ba1[j];
    float a2 = 0.f;
    const float* srow = scalars + (size_t)n * 64;
#pragma unroll 8
    for (int k = 0; k < 64; k++) {
        float s = srow[k];
        a1 = fmaf(s, Wa1[k * 64 + j], a1);
        a2 = fmaf(s, Wa1[(64 + k) * 64 + j], a2);
    }
    P1[t] = a1;
    P2[t] = a2;
}

// ================= CSR build (round-3 proven versions) =================
__global__ void k_hist(const int* __restrict__ eidx, int* __restrict__ cnt)
{
    int e = blockIdx.x * 256 + threadIdx.x;
    atomicAdd(&cnt[eidx[E_ + e]], 1);
}

__global__ void k_scan(const int* __restrict__ cnt, int* __restrict__ row_start)
{
    __shared__ int buf[1024];
    __shared__ int carry;
    int tid = threadIdx.x;
    if (tid == 0) carry = 0;
    __syncthreads();
    for (int c = 0; c < 40; ++c) {   // 40*1024 = 40960 >= N_
        int idx = c * 1024 + tid;
        int v = (idx < N_) ? cnt[idx] : 0;
        buf[tid] = v;
        __syncthreads();
        for (int off = 1; off < 1024; off <<= 1) {
            int t = (tid >= off) ? buf[tid - off] : 0;
            __syncthreads();
            buf[tid] += t;
            __syncthreads();
        }
        if (idx < N_) row_start[idx] = carry + buf[tid] - v;  // exclusive
        __syncthreads();
        if (tid == 1023) carry += buf[1023];
        __syncthreads();
    }
    if (tid == 0) row_start[N_] = carry;  // == E_
}

__global__ void k_scatter(const int* __restrict__ eidx, const int* __restrict__ row_start,
                          int* __restrict__ c2, int* __restrict__ perm)
{
    int e = blockIdx.x * 256 + threadIdx.x;
    int dst = eidx[E_ + e];
    int pos = row_start[dst] + atomicAdd(&c2[dst], 1);
    perm[pos] = e;
}

// ================= edge phase (round-3 proven) =================
__global__ __launch_bounds__(256, 2) void k_edges_sorted(
    const float* __restrict__ edge_vec, const int* __restrict__ eidx,
    const int* __restrict__ perm,
    const float* __restrict__ P1, const float* __restrict__ P2,
    const float* __restrict__ W1, const float* __restrict__ b1,
    const float* __restrict__ Wa1, const float* __restrict__ Wa2,
    const float* __restrict__ ba2,
    float4* __restrict__ attsh, int* __restrict__ srcbuf, float* __restrict__ hbuf)
{
    int i = blockIdx.x * 256 + threadIdx.x;
    int e = perm[i];
    int src = eidx[e];
    int dst = eidx[E_ + e];

    float ev0 = edge_vec[3 * e + 0];
    float ev1 = edge_vec[3 * e + 1];
    float ev2 = edge_vec[3 * e + 2];
    float d = sqrtf(fmaf(ev0, ev0, fmaf(ev1, ev1, ev2 * ev2)));
    float inv_d = __fdividef(1.f, fmaxf(d, 1e-8f));
    float cut = (d < 10.f) ? 0.5f * (__cosf(0.31415927f * d) + 1.f) : 0.f;
    float cutd = cut * inv_d;
    float sh0 = ev1 * inv_d, sh1 = ev2 * inv_d, sh2 = ev0 * inv_d;  // [uy, uz, ux]

    float g[96];
#pragma unroll
    for (int j = 0; j < 96; j++) g[j] = 0.f;
    for (int k = 0; k < 32; k++) {
        float rk = __sinf((float)(k + 1) * 0.31415927f * d) * cutd;
        const float* wa = Wa1 + (128 + k) * 64;
        const float* w1 = W1 + k * 32;
#pragma unroll
        for (int j = 0; j < 64; j++) g[j] = fmaf(rk, wa[j], g[j]);
#pragma unroll
        for (int j = 0; j < 32; j++) g[64 + j] = fmaf(rk, w1[j], g[64 + j]);
    }

    const float* p1 = P1 + (size_t)dst * 64;
    const float* p2 = P2 + (size_t)src * 64;
    float logit = ba2[0];
#pragma unroll
    for (int j = 0; j < 64; j++) {
        float aj = p1[j] + p2[j] + g[j];
        logit = fmaf(silu_f(aj), Wa2[j], logit);
    }
    float att = __fdividef(1.f, 1.f + __expf(-logit));

    float* hrow = hbuf + (size_t)i * 32;
#pragma unroll
    for (int k = 0; k < 32; k++) hrow[k] = silu_f(g[64 + k] + b1[k]);

    attsh[i] = make_float4(att, sh0, sh1, sh2);
    srcbuf[i] = src;
}

// ================= gather: ONLY change vs round 5 — readfirstlane-forced SMEM loads =================
// rs/re pass through readfirstlane, so the edge index i and every address derived from it
// (attsh[i], srcbuf[i], hbuf+i*32) are compiler-provably wave-uniform -> scalar s_load path,
// eliminating the broadcast vector-load return-bandwidth bound measured in rounds 3/5.
__global__ __launch_bounds__(256, 4) void k_gather(
    const float* __restrict__ scalars, const float* __restrict__ vectors,
    const float* __restrict__ W2, const float* __restrict__ b2,
    const int* __restrict__ row_start,
    const float4* __restrict__ attsh, const int* __restrict__ srcbuf,
    const float* __restrict__ hbuf,
    float* __restrict__ out)
{
    int wid  = threadIdx.x >> 6;
    int lane = threadIdx.x & 63;
    int n    = blockIdx.x * 2 + (wid >> 1);
    int role = wid & 1;
    int rs = rfl(row_start[n]);
    int re = rfl(row_start[n + 1]);

    if (role == 0) {
        float wj[32];
#pragma unroll
        for (int k = 0; k < 32; k++) wj[k] = W2[k * 96 + lane];
        float bj = b2[lane];
        float acc = 0.f;
        int i = rs;
        for (; i + 2 <= re; i += 2) {
            const float* h0 = hbuf + (size_t)i * 32;
            const float* h1 = h0 + 32;
            float4 as0 = attsh[i + 0];
            float4 as1 = attsh[i + 1];
            int s0 = srcbuf[i + 0];
            int s1 = srcbuf[i + 1];
            float g0 = scalars[(size_t)s0 * 64 + lane];
            float g1 = scalars[(size_t)s1 * 64 + lane];
            float f0 = bj, f1 = bj;
#pragma unroll
            for (int k = 0; k < 32; k++) {
                f0 = fmaf(h0[k], wj[k], f0);
                f1 = fmaf(h1[k], wj[k], f1);
            }
            acc = fmaf(as0.x * g0, f0, acc);
            acc = fmaf(as1.x * g1, f1, acc);
        }
        if (i < re) {
            const float* h0 = hbuf + (size_t)i * 32;
            float4 as = attsh[i];
            int s0 = srcbuf[i];
            float f = bj;
#pragma unroll
            for (int k = 0; k < 32; k++) f = fmaf(h0[k], wj[k], f);
            acc = fmaf(as.x * scalars[(size_t)s0 * 64 + lane], f, acc);
        }
        out[(size_t)n * 64 + lane] = scalars[(size_t)n * 64 + lane] + acc;
    } else if (lane < 48) {
        int m = lane / 3;
        int c = lane - 3 * m;
        float wf[32], wg[32];
#pragma unroll
        for (int k = 0; k < 32; k++) {
            wf[k] = W2[k * 96 + 64 + m];
            wg[k] = W2[k * 96 + 80 + m];
        }
        float bf = b2[64 + m], bg = b2[80 + m];
        float acc = 0.f;
        int i = rs;
        for (; i + 2 <= re; i += 2) {
            const float* h0 = hbuf + (size_t)i * 32;
            const float* h1 = h0 + 32;
            float4 as0 = attsh[i + 0];
            float4 as1 = attsh[i + 1];
            int s0 = srcbuf[i + 0];
            int s1 = srcbuf[i + 1];
            float vj0 = vectors[(size_t)s0 * 48 + lane];
            float vj1 = vectors[(size_t)s1 * 48 + lane];
            float vf0 = bf, vg0 = bg, vf1 = bf, vg1 = bg;
#pragma unroll
            for (int k = 0; k < 32; k++) {
                float a0 = h0[k], a1 = h1[k];
                vf0 = fmaf(a0, wf[k], vf0); vg0 = fmaf(a0, wg[k], vg0);
                vf1 = fmaf(a1, wf[k], vf1); vg1 = fmaf(a1, wg[k], vg1);
            }
            float sh0c = (c == 0) ? as0.y : ((c == 1) ? as0.z : as0.w);
            float sh1c = (c == 0) ? as1.y : ((c == 1) ? as1.z : as1.w);
            acc = fmaf(as0.x, fmaf(vj0, vf0, vg0 * sh0c), acc);
            acc = fmaf(as1.x, fmaf(vj1, vf1, vg1 * sh1c), acc);
        }
        if (i < re) {
            const float* h0 = hbuf + (size_t)i * 32;
            float4 as = attsh[i];
            int s0 = srcbuf[i];
            float vjc = vectors[(size_t)s0 * 48 + lane];
            float vf = bf, vg = bg;
#pragma unroll
            for (int k = 0; k < 32; k++) {
                float a = h0[k];
                vf = fmaf(a, wf[k], vf); vg = fmaf(a, wg[k], vg);
            }
            float shc = (c == 0) ? as.y : ((c == 1) ? as.z : as.w);
            acc = fmaf(as.x, fmaf(vjc, vf, vg * shc), acc);
        }
        out[NS + (size_t)n * 48 + lane] = vectors[(size_t)n * 48 + lane] + acc;
    }
}

extern "C" void kernel_launch(void* const* d_in, const int* in_sizes, int n_in,
                              void* d_out, int out_size, void* d_ws, size_t ws_size,
                              hipStream_t stream)
{
    const float* scalars  = (const float*)d_in[0];
    const float* vectors  = (const float*)d_in[1];
    const float* edge_vec = (const float*)d_in[2];
    const float* W1  = (const float*)d_in[3];
    const float* b1  = (const float*)d_in[4];
    const float* W2  = (const float*)d_in[5];
    const float* b2  = (const float*)d_in[6];
    const float* Wa1 = (const float*)d_in[7];
    const float* ba1 = (const float*)d_in[8];
    const float* Wa2 = (const float*)d_in[9];
    const float* ba2 = (const float*)d_in[10];
    const int* eidx  = (const int*)d_in[11];

    char* wsb = (char*)d_ws;
    // round-3 proven layout: attsh | P1 | P2 | hbuf | cnt | c2 | row_start | perm | srcbuf
    float4* attsh = (float4*)wsb;                       // E float4      = 20.48 MB
    float*  P1    = (float*)(wsb + (size_t)E_ * 16);    // NS floats     = 10.24 MB
    float*  P2    = P1 + NS;                            // NS floats     = 10.24 MB
    float*  hbuf  = P2 + NS;                            // 32E floats    = 163.84 MB
    int* cnt       = (int*)(hbuf + (size_t)32 * E_);    // N
    int* c2        = cnt + N_;                          // N
    int* row_start = c2 + N_;                           // N+1
    int* perm      = row_start + N_ + 1;                // E
    int* srcbuf    = perm + E_;                         // E  (end ~215.6 MB; round 3 proved ws fits)

    hipMemsetAsync(cnt, 0, (size_t)2 * N_ * sizeof(int), stream);   // cnt + c2
    k_hist<<<5000, 256, 0, stream>>>(eidx, cnt);
    k_scan<<<1, 1024, 0, stream>>>(cnt, row_start);
    k_scatter<<<5000, 256, 0, stream>>>(eidx, row_start, c2, perm);
    k_precompute<<<10000, 256, 0, stream>>>(scalars, Wa1, ba1, P1, P2);
    k_edges_sorted<<<5000, 256, 0, stream>>>(edge_vec, eidx, perm, P1, P2,
                                             W1, b1, Wa1, Wa2, ba2,
                                             attsh, srcbuf, hbuf);
    k_gather<<<20000, 256, 0, stream>>>(scalars, vectors, W2, b2, row_start,
                                        attsh, srcbuf, hbuf, (float*)d_out);
}

// Round 7
// 843.060 us; speedup vs baseline: 1.6379x; 1.0070x over previous
//
#include <hip/hip_runtime.h>

static constexpr int N_ = 40000;
static constexpr int E_ = 1280000;
static constexpr int NS = N_ * 64;      // 2,560,000 scalar elems
static constexpr int NV = N_ * 48;      // 1,920,000 vector elems

__device__ __forceinline__ float silu_f(float x) { return __fdividef(x, 1.f + __expf(-x)); }
__device__ __forceinline__ int rfl(int x) { return __builtin_amdgcn_readfirstlane(x); }

// ---- per-node attention precompute ----
// P1[n][j] = ba1[j] + sum_k s[n][k]*Wa1[k][j]      (s_i / dst part)
// P2[n][j] =          sum_k s[n][k]*Wa1[64+k][j]   (s_j / src part)
__global__ void k_precompute(const float* __restrict__ scalars, const float* __restrict__ Wa1,
                             const float* __restrict__ ba1,
                             float* __restrict__ P1, float* __restrict__ P2)
{
    int t = blockIdx.x * 256 + threadIdx.x;  // t < N*64
    int n = t >> 6, j = t & 63;
    float a1 = ba1[j];
    float a2 = 0.f;
    const float* srow = scalars + (size_t)n * 64;
#pragma unroll 8
    for (int k = 0; k < 64; k++) {
        float s = srow[k];
        a1 = fmaf(s, Wa1[k * 64 + j], a1);
        a2 = fmaf(s, Wa1[(64 + k) * 64 + j], a2);
    }
    P1[t] = a1;
    P2[t] = a2;
}

// ================= CSR build (round-3 proven versions) =================
__global__ void k_hist(const int* __restrict__ eidx, int* __restrict__ cnt)
{
    int e = blockIdx.x * 256 + threadIdx.x;
    atomicAdd(&cnt[eidx[E_ + e]], 1);
}

__global__ void k_scan(const int* __restrict__ cnt, int* __restrict__ row_start)
{
    __shared__ int buf[1024];
    __shared__ int carry;
    int tid = threadIdx.x;
    if (tid == 0) carry = 0;
    __syncthreads();
    for (int c = 0; c < 40; ++c) {   // 40*1024 = 40960 >= N_
        int idx = c * 1024 + tid;
        int v = (idx < N_) ? cnt[idx] : 0;
        buf[tid] = v;
        __syncthreads();
        for (int off = 1; off < 1024; off <<= 1) {
            int t = (tid >= off) ? buf[tid - off] : 0;
            __syncthreads();
            buf[tid] += t;
            __syncthreads();
        }
        if (idx < N_) row_start[idx] = carry + buf[tid] - v;  // exclusive
        __syncthreads();
        if (tid == 1023) carry += buf[1023];
        __syncthreads();
    }
    if (tid == 0) row_start[N_] = carry;  // == E_
}

__global__ void k_scatter(const int* __restrict__ eidx, const int* __restrict__ row_start,
                          int* __restrict__ c2, int* __restrict__ perm)
{
    int e = blockIdx.x * 256 + threadIdx.x;
    int dst = eidx[E_ + e];
    int pos = row_start[dst] + atomicAdd(&c2[dst], 1);
    perm[pos] = e;
}

// ================= edge phase (round-3 proven) =================
__global__ __launch_bounds__(256, 2) void k_edges_sorted(
    const float* __restrict__ edge_vec, const int* __restrict__ eidx,
    const int* __restrict__ perm,
    const float* __restrict__ P1, const float* __restrict__ P2,
    const float* __restrict__ W1, const float* __restrict__ b1,
    const float* __restrict__ Wa1, const float* __restrict__ Wa2,
    const float* __restrict__ ba2,
    float4* __restrict__ attsh, int* __restrict__ srcbuf, float* __restrict__ hbuf)
{
    int i = blockIdx.x * 256 + threadIdx.x;
    int e = perm[i];
    int src = eidx[e];
    int dst = eidx[E_ + e];

    float ev0 = edge_vec[3 * e + 0];
    float ev1 = edge_vec[3 * e + 1];
    float ev2 = edge_vec[3 * e + 2];
    float d = sqrtf(fmaf(ev0, ev0, fmaf(ev1, ev1, ev2 * ev2)));
    float inv_d = __fdividef(1.f, fmaxf(d, 1e-8f));
    float cut = (d < 10.f) ? 0.5f * (__cosf(0.31415927f * d) + 1.f) : 0.f;
    float cutd = cut * inv_d;
    float sh0 = ev1 * inv_d, sh1 = ev2 * inv_d, sh2 = ev0 * inv_d;  // [uy, uz, ux]

    float g[96];
#pragma unroll
    for (int j = 0; j < 96; j++) g[j] = 0.f;
    for (int k = 0; k < 32; k++) {
        float rk = __sinf((float)(k + 1) * 0.31415927f * d) * cutd;
        const float* wa = Wa1 + (128 + k) * 64;
        const float* w1 = W1 + k * 32;
#pragma unroll
        for (int j = 0; j < 64; j++) g[j] = fmaf(rk, wa[j], g[j]);
#pragma unroll
        for (int j = 0; j < 32; j++) g[64 + j] = fmaf(rk, w1[j], g[64 + j]);
    }

    const float* p1 = P1 + (size_t)dst * 64;
    const float* p2 = P2 + (size_t)src * 64;
    float logit = ba2[0];
#pragma unroll
    for (int j = 0; j < 64; j++) {
        float aj = p1[j] + p2[j] + g[j];
        logit = fmaf(silu_f(aj), Wa2[j], logit);
    }
    float att = __fdividef(1.f, 1.f + __expf(-logit));

    float* hrow = hbuf + (size_t)i * 32;
#pragma unroll
    for (int k = 0; k < 32; k++) hrow[k] = silu_f(g[64 + k] + b1[k]);

    attsh[i] = make_float4(att, sh0, sh1, sh2);
    srcbuf[i] = src;
}

// ================= gather: vs round 6, ONLY role-1 changed — shuffle-dedup of vf/vg dots =====
// Role-1 lanes 0-15 compute the vf[m]=h@W2[:,64+m] dot, lanes 16-31 the vg[m]=h@W2[:,80+m]
// dot (single unified 32-FMA loop), then ds_bpermute (__shfl) distributes vf[m]/vg[m] to the
// 48 (m,c) message lanes. Removes the 3x per-lane duplication + halves role-1 dot count.
__global__ __launch_bounds__(256, 4) void k_gather(
    const float* __restrict__ scalars, const float* __restrict__ vectors,
    const float* __restrict__ W2, const float* __restrict__ b2,
    const int* __restrict__ row_start,
    const float4* __restrict__ attsh, const int* __restrict__ srcbuf,
    const float* __restrict__ hbuf,
    float* __restrict__ out)
{
    int wid  = threadIdx.x >> 6;
    int lane = threadIdx.x & 63;
    int n    = blockIdx.x * 2 + (wid >> 1);
    int role = wid & 1;
    int rs = rfl(row_start[n]);
    int re = rfl(row_start[n + 1]);

    if (role == 0) {
        float wj[32];
#pragma unroll
        for (int k = 0; k < 32; k++) wj[k] = W2[k * 96 + lane];
        float bj = b2[lane];
        float acc = 0.f;
        int i = rs;
        for (; i + 2 <= re; i += 2) {
            const float* h0 = hbuf + (size_t)i * 32;
            const float* h1 = h0 + 32;
            float4 as0 = attsh[i + 0];
            float4 as1 = attsh[i + 1];
            int s0 = srcbuf[i + 0];
            int s1 = srcbuf[i + 1];
            float g0 = scalars[(size_t)s0 * 64 + lane];
            float g1 = scalars[(size_t)s1 * 64 + lane];
            float f0 = bj, f1 = bj;
#pragma unroll
            for (int k = 0; k < 32; k++) {
                f0 = fmaf(h0[k], wj[k], f0);
                f1 = fmaf(h1[k], wj[k], f1);
            }
            acc = fmaf(as0.x * g0, f0, acc);
            acc = fmaf(as1.x * g1, f1, acc);
        }
        if (i < re) {
            const float* h0 = hbuf + (size_t)i * 32;
            float4 as = attsh[i];
            int s0 = srcbuf[i];
            float f = bj;
#pragma unroll
            for (int k = 0; k < 32; k++) f = fmaf(h0[k], wj[k], f);
            acc = fmaf(as.x * scalars[(size_t)s0 * 64 + lane], f, acc);
        }
        out[(size_t)n * 64 + lane] = scalars[(size_t)n * 64 + lane] + acc;
    } else {
        int m_src = lane / 3;                 // lanes 0-47: message (m,c); 48-63: junk (unused)
        int c     = lane - 3 * m_src;
        int lsel  = (lane < 48) ? lane : 47;  // clamp to stay in-bounds for vj loads
        // unified dot weights: lanes 0-15 -> vf col (64+m), lanes 16-31 -> vg col (80+m),
        // lanes 32-63 -> duplicate of vf cols (harmless, never shuffled from)
        int col = (lane < 16) ? (64 + lane) : ((lane < 32) ? (80 + (lane - 16)) : (64 + (lane & 15)));
        float wv[32];
#pragma unroll
        for (int k = 0; k < 32; k++) wv[k] = W2[k * 96 + col];
        float bv = b2[col];
        float acc = 0.f;
        int i = rs;
        for (; i + 2 <= re; i += 2) {
            const float* h0 = hbuf + (size_t)i * 32;
            const float* h1 = h0 + 32;
            float4 as0 = attsh[i + 0];
            float4 as1 = attsh[i + 1];
            int s0 = srcbuf[i + 0];
            int s1 = srcbuf[i + 1];
            float vj0 = vectors[(size_t)s0 * 48 + lsel];
            float vj1 = vectors[(size_t)s1 * 48 + lsel];
            float fv0 = bv, fv1 = bv;
#pragma unroll
            for (int k = 0; k < 32; k++) {
                fv0 = fmaf(h0[k], wv[k], fv0);
                fv1 = fmaf(h1[k], wv[k], fv1);
            }
            float vf0 = __shfl(fv0, m_src, 64);
            float vg0 = __shfl(fv0, 16 + m_src, 64);
            float vf1 = __shfl(fv1, m_src, 64);
            float vg1 = __shfl(fv1, 16 + m_src, 64);
            float sh0c = (c == 0) ? as0.y : ((c == 1) ? as0.z : as0.w);
            float sh1c = (c == 0) ? as1.y : ((c == 1) ? as1.z : as1.w);
            acc = fmaf(as0.x, fmaf(vj0, vf0, vg0 * sh0c), acc);
            acc = fmaf(as1.x, fmaf(vj1, vf1, vg1 * sh1c), acc);
        }
        if (i < re) {
            const float* h0 = hbuf + (size_t)i * 32;
            float4 as = attsh[i];
            int s0 = srcbuf[i];
            float vjc = vectors[(size_t)s0 * 48 + lsel];
            float fv = bv;
#pragma unroll
            for (int k = 0; k < 32; k++) fv = fmaf(h0[k], wv[k], fv);
            float vf = __shfl(fv, m_src, 64);
            float vg = __shfl(fv, 16 + m_src, 64);
            float shc = (c == 0) ? as.y : ((c == 1) ? as.z : as.w);
            acc = fmaf(as.x, fmaf(vjc, vf, vg * shc), acc);
        }
        if (lane < 48)
            out[NS + (size_t)n * 48 + lane] = vectors[(size_t)n * 48 + lane] + acc;
    }
}

extern "C" void kernel_launch(void* const* d_in, const int* in_sizes, int n_in,
                              void* d_out, int out_size, void* d_ws, size_t ws_size,
                              hipStream_t stream)
{
    const float* scalars  = (const float*)d_in[0];
    const float* vectors  = (const float*)d_in[1];
    const float* edge_vec = (const float*)d_in[2];
    const float* W1  = (const float*)d_in[3];
    const float* b1  = (const float*)d_in[4];
    const float* W2  = (const float*)d_in[5];
    const float* b2  = (const float*)d_in[6];
    const float* Wa1 = (const float*)d_in[7];
    const float* ba1 = (const float*)d_in[8];
    const float* Wa2 = (const float*)d_in[9];
    const float* ba2 = (const float*)d_in[10];
    const int* eidx  = (const int*)d_in[11];

    char* wsb = (char*)d_ws;
    // round-3 proven layout: attsh | P1 | P2 | hbuf | cnt | c2 | row_start | perm | srcbuf
    float4* attsh = (float4*)wsb;                       // E float4      = 20.48 MB
    float*  P1    = (float*)(wsb + (size_t)E_ * 16);    // NS floats     = 10.24 MB
    float*  P2    = P1 + NS;                            // NS floats     = 10.24 MB
    float*  hbuf  = P2 + NS;                            // 32E floats    = 163.84 MB
    int* cnt       = (int*)(hbuf + (size_t)32 * E_);    // N
    int* c2        = cnt + N_;                          // N
    int* row_start = c2 + N_;                           // N+1
    int* perm      = row_start + N_ + 1;                // E
    int* srcbuf    = perm + E_;                         // E  (end ~215.6 MB; round 3 proved ws fits)

    hipMemsetAsync(cnt, 0, (size_t)2 * N_ * sizeof(int), stream);   // cnt + c2
    k_hist<<<5000, 256, 0, stream>>>(eidx, cnt);
    k_scan<<<1, 1024, 0, stream>>>(cnt, row_start);
    k_scatter<<<5000, 256, 0, stream>>>(eidx, row_start, c2, perm);
    k_precompute<<<10000, 256, 0, stream>>>(scalars, Wa1, ba1, P1, P2);
    k_edges_sorted<<<5000, 256, 0, stream>>>(edge_vec, eidx, perm, P1, P2,
                                             W1, b1, Wa1, Wa2, ba2,
                                             attsh, srcbuf, hbuf);
    k_gather<<<20000, 256, 0, stream>>>(scalars, vectors, W2, b2, row_start,
                                        attsh, srcbuf, hbuf, (float*)d_out);
}

// Round 8
// 823.710 us; speedup vs baseline: 1.6764x; 1.0235x over previous
//
#include <hip/hip_runtime.h>

static constexpr int N_ = 40000;
static constexpr int E_ = 1280000;
static constexpr int NS = N_ * 64;      // 2,560,000 scalar elems
static constexpr int NV = N_ * 48;      // 1,920,000 vector elems

__device__ __forceinline__ float silu_f(float x) { return __fdividef(x, 1.f + __expf(-x)); }
__device__ __forceinline__ int rfl(int x) { return __builtin_amdgcn_readfirstlane(x); }

// ---- per-node attention precompute ----
// P1[n][j] = ba1[j] + sum_k s[n][k]*Wa1[k][j]      (s_i / dst part)
// P2[n][j] =          sum_k s[n][k]*Wa1[64+k][j]   (s_j / src part)
__global__ void k_precompute(const float* __restrict__ scalars, const float* __restrict__ Wa1,
                             const float* __restrict__ ba1,
                             float* __restrict__ P1, float* __restrict__ P2)
{
    int t = blockIdx.x * 256 + threadIdx.x;  // t < N*64
    int n = t >> 6, j = t & 63;
    float a1 = ba1[j];
    float a2 = 0.f;
    const float* srow = scalars + (size_t)n * 64;
#pragma unroll 8
    for (int k = 0; k < 64; k++) {
        float s = srow[k];
        a1 = fmaf(s, Wa1[k * 64 + j], a1);
        a2 = fmaf(s, Wa1[(64 + k) * 64 + j], a2);
    }
    P1[t] = a1;
    P2[t] = a2;
}

// ================= CSR build (round-3 proven versions) =================
__global__ void k_hist(const int* __restrict__ eidx, int* __restrict__ cnt)
{
    int e = blockIdx.x * 256 + threadIdx.x;
    atomicAdd(&cnt[eidx[E_ + e]], 1);
}

__global__ void k_scan(const int* __restrict__ cnt, int* __restrict__ row_start)
{
    __shared__ int buf[1024];
    __shared__ int carry;
    int tid = threadIdx.x;
    if (tid == 0) carry = 0;
    __syncthreads();
    for (int c = 0; c < 40; ++c) {   // 40*1024 = 40960 >= N_
        int idx = c * 1024 + tid;
        int v = (idx < N_) ? cnt[idx] : 0;
        buf[tid] = v;
        __syncthreads();
        for (int off = 1; off < 1024; off <<= 1) {
            int t = (tid >= off) ? buf[tid - off] : 0;
            __syncthreads();
            buf[tid] += t;
            __syncthreads();
        }
        if (idx < N_) row_start[idx] = carry + buf[tid] - v;  // exclusive
        __syncthreads();
        if (tid == 1023) carry += buf[1023];
        __syncthreads();
    }
    if (tid == 0) row_start[N_] = carry;  // == E_
}

__global__ void k_scatter(const int* __restrict__ eidx, const int* __restrict__ row_start,
                          int* __restrict__ c2, int* __restrict__ perm)
{
    int e = blockIdx.x * 256 + threadIdx.x;
    int dst = eidx[E_ + e];
    int pos = row_start[dst] + atomicAdd(&c2[dst], 1);
    perm[pos] = e;
}

// ================= edge phase: vs round 7 ONLY float4 p1/p2 loads + float4 h stores =======
// The logit loop previously issued 64+64 scalar gathers (each wave: 64 distinct 64B sectors
// per inst, 16x redundant sector fetches). float4 cuts gather-inst count 4x at identical
// arithmetic order.
__global__ __launch_bounds__(256, 2) void k_edges_sorted(
    const float* __restrict__ edge_vec, const int* __restrict__ eidx,
    const int* __restrict__ perm,
    const float* __restrict__ P1, const float* __restrict__ P2,
    const float* __restrict__ W1, const float* __restrict__ b1,
    const float* __restrict__ Wa1, const float* __restrict__ Wa2,
    const float* __restrict__ ba2,
    float4* __restrict__ attsh, int* __restrict__ srcbuf, float* __restrict__ hbuf)
{
    int i = blockIdx.x * 256 + threadIdx.x;
    int e = perm[i];
    int src = eidx[e];
    int dst = eidx[E_ + e];

    float ev0 = edge_vec[3 * e + 0];
    float ev1 = edge_vec[3 * e + 1];
    float ev2 = edge_vec[3 * e + 2];
    float d = sqrtf(fmaf(ev0, ev0, fmaf(ev1, ev1, ev2 * ev2)));
    float inv_d = __fdividef(1.f, fmaxf(d, 1e-8f));
    float cut = (d < 10.f) ? 0.5f * (__cosf(0.31415927f * d) + 1.f) : 0.f;
    float cutd = cut * inv_d;
    float sh0 = ev1 * inv_d, sh1 = ev2 * inv_d, sh2 = ev0 * inv_d;  // [uy, uz, ux]

    float g[96];
#pragma unroll
    for (int j = 0; j < 96; j++) g[j] = 0.f;
    for (int k = 0; k < 32; k++) {
        float rk = __sinf((float)(k + 1) * 0.31415927f * d) * cutd;
        const float* wa = Wa1 + (128 + k) * 64;
        const float* w1 = W1 + k * 32;
#pragma unroll
        for (int j = 0; j < 64; j++) g[j] = fmaf(rk, wa[j], g[j]);
#pragma unroll
        for (int j = 0; j < 32; j++) g[64 + j] = fmaf(rk, w1[j], g[64 + j]);
    }

    const float4* p14 = (const float4*)(P1 + (size_t)dst * 64);
    const float4* p24 = (const float4*)(P2 + (size_t)src * 64);
    float logit = ba2[0];
#pragma unroll
    for (int q = 0; q < 16; q++) {
        float4 a = p14[q];
        float4 b = p24[q];
        float aj0 = a.x + b.x + g[4 * q + 0];
        logit = fmaf(silu_f(aj0), Wa2[4 * q + 0], logit);
        float aj1 = a.y + b.y + g[4 * q + 1];
        logit = fmaf(silu_f(aj1), Wa2[4 * q + 1], logit);
        float aj2 = a.z + b.z + g[4 * q + 2];
        logit = fmaf(silu_f(aj2), Wa2[4 * q + 2], logit);
        float aj3 = a.w + b.w + g[4 * q + 3];
        logit = fmaf(silu_f(aj3), Wa2[4 * q + 3], logit);
    }
    float att = __fdividef(1.f, 1.f + __expf(-logit));

    float4* hrow4 = (float4*)(hbuf + (size_t)i * 32);
#pragma unroll
    for (int q = 0; q < 8; q++) {
        hrow4[q] = make_float4(silu_f(g[64 + 4 * q + 0] + b1[4 * q + 0]),
                               silu_f(g[64 + 4 * q + 1] + b1[4 * q + 1]),
                               silu_f(g[64 + 4 * q + 2] + b1[4 * q + 2]),
                               silu_f(g[64 + 4 * q + 3] + b1[4 * q + 3]));
    }

    attsh[i] = make_float4(att, sh0, sh1, sh2);
    srcbuf[i] = src;
}

// ================= gather (round-7 proven, unchanged) =================
__global__ __launch_bounds__(256, 4) void k_gather(
    const float* __restrict__ scalars, const float* __restrict__ vectors,
    const float* __restrict__ W2, const float* __restrict__ b2,
    const int* __restrict__ row_start,
    const float4* __restrict__ attsh, const int* __restrict__ srcbuf,
    const float* __restrict__ hbuf,
    float* __restrict__ out)
{
    int wid  = threadIdx.x >> 6;
    int lane = threadIdx.x & 63;
    int n    = blockIdx.x * 2 + (wid >> 1);
    int role = wid & 1;
    int rs = rfl(row_start[n]);
    int re = rfl(row_start[n + 1]);

    if (role == 0) {
        float wj[32];
#pragma unroll
        for (int k = 0; k < 32; k++) wj[k] = W2[k * 96 + lane];
        float bj = b2[lane];
        float acc = 0.f;
        int i = rs;
        for (; i + 2 <= re; i += 2) {
            const float* h0 = hbuf + (size_t)i * 32;
            const float* h1 = h0 + 32;
            float4 as0 = attsh[i + 0];
            float4 as1 = attsh[i + 1];
            int s0 = srcbuf[i + 0];
            int s1 = srcbuf[i + 1];
            float g0 = scalars[(size_t)s0 * 64 + lane];
            float g1 = scalars[(size_t)s1 * 64 + lane];
            float f0 = bj, f1 = bj;
#pragma unroll
            for (int k = 0; k < 32; k++) {
                f0 = fmaf(h0[k], wj[k], f0);
                f1 = fmaf(h1[k], wj[k], f1);
            }
            acc = fmaf(as0.x * g0, f0, acc);
            acc = fmaf(as1.x * g1, f1, acc);
        }
        if (i < re) {
            const float* h0 = hbuf + (size_t)i * 32;
            float4 as = attsh[i];
            int s0 = srcbuf[i];
            float f = bj;
#pragma unroll
            for (int k = 0; k < 32; k++) f = fmaf(h0[k], wj[k], f);
            acc = fmaf(as.x * scalars[(size_t)s0 * 64 + lane], f, acc);
        }
        out[(size_t)n * 64 + lane] = scalars[(size_t)n * 64 + lane] + acc;
    } else {
        int m_src = lane / 3;                 // lanes 0-47: message (m,c); 48-63: junk (unused)
        int c     = lane - 3 * m_src;
        int lsel  = (lane < 48) ? lane : 47;  // clamp to stay in-bounds for vj loads
        int col = (lane < 16) ? (64 + lane) : ((lane < 32) ? (80 + (lane - 16)) : (64 + (lane & 15)));
        float wv[32];
#pragma unroll
        for (int k = 0; k < 32; k++) wv[k] = W2[k * 96 + col];
        float bv = b2[col];
        float acc = 0.f;
        int i = rs;
        for (; i + 2 <= re; i += 2) {
            const float* h0 = hbuf + (size_t)i * 32;
            const float* h1 = h0 + 32;
            float4 as0 = attsh[i + 0];
            float4 as1 = attsh[i + 1];
            int s0 = srcbuf[i + 0];
            int s1 = srcbuf[i + 1];
            float vj0 = vectors[(size_t)s0 * 48 + lsel];
            float vj1 = vectors[(size_t)s1 * 48 + lsel];
            float fv0 = bv, fv1 = bv;
#pragma unroll
            for (int k = 0; k < 32; k++) {
                fv0 = fmaf(h0[k], wv[k], fv0);
                fv1 = fmaf(h1[k], wv[k], fv1);
            }
            float vf0 = __shfl(fv0, m_src, 64);
            float vg0 = __shfl(fv0, 16 + m_src, 64);
            float vf1 = __shfl(fv1, m_src, 64);
            float vg1 = __shfl(fv1, 16 + m_src, 64);
            float sh0c = (c == 0) ? as0.y : ((c == 1) ? as0.z : as0.w);
            float sh1c = (c == 0) ? as1.y : ((c == 1) ? as1.z : as1.w);
            acc = fmaf(as0.x, fmaf(vj0, vf0, vg0 * sh0c), acc);
            acc = fmaf(as1.x, fmaf(vj1, vf1, vg1 * sh1c), acc);
        }
        if (i < re) {
            const float* h0 = hbuf + (size_t)i * 32;
            float4 as = attsh[i];
            int s0 = srcbuf[i];
            float vjc = vectors[(size_t)s0 * 48 + lsel];
            float fv = bv;
#pragma unroll
            for (int k = 0; k < 32; k++) fv = fmaf(h0[k], wv[k], fv);
            float vf = __shfl(fv, m_src, 64);
            float vg = __shfl(fv, 16 + m_src, 64);
            float shc = (c == 0) ? as.y : ((c == 1) ? as.z : as.w);
            acc = fmaf(as.x, fmaf(vjc, vf, vg * shc), acc);
        }
        if (lane < 48)
            out[NS + (size_t)n * 48 + lane] = vectors[(size_t)n * 48 + lane] + acc;
    }
}

extern "C" void kernel_launch(void* const* d_in, const int* in_sizes, int n_in,
                              void* d_out, int out_size, void* d_ws, size_t ws_size,
                              hipStream_t stream)
{
    const float* scalars  = (const float*)d_in[0];
    const float* vectors  = (const float*)d_in[1];
    const float* edge_vec = (const float*)d_in[2];
    const float* W1  = (const float*)d_in[3];
    const float* b1  = (const float*)d_in[4];
    const float* W2  = (const float*)d_in[5];
    const float* b2  = (const float*)d_in[6];
    const float* Wa1 = (const float*)d_in[7];
    const float* ba1 = (const float*)d_in[8];
    const float* Wa2 = (const float*)d_in[9];
    const float* ba2 = (const float*)d_in[10];
    const int* eidx  = (const int*)d_in[11];

    char* wsb = (char*)d_ws;
    // round-3 proven layout: attsh | P1 | P2 | hbuf | cnt | c2 | row_start | perm | srcbuf
    float4* attsh = (float4*)wsb;                       // E float4      = 20.48 MB
    float*  P1    = (float*)(wsb + (size_t)E_ * 16);    // NS floats     = 10.24 MB
    float*  P2    = P1 + NS;                            // NS floats     = 10.24 MB
    float*  hbuf  = P2 + NS;                            // 32E floats    = 163.84 MB
    int* cnt       = (int*)(hbuf + (size_t)32 * E_);    // N
    int* c2        = cnt + N_;                          // N
    int* row_start = c2 + N_;                           // N+1
    int* perm      = row_start + N_ + 1;                // E
    int* srcbuf    = perm + E_;                         // E  (end ~215.6 MB; round 3 proved ws fits)

    hipMemsetAsync(cnt, 0, (size_t)2 * N_ * sizeof(int), stream);   // cnt + c2
    k_hist<<<5000, 256, 0, stream>>>(eidx, cnt);
    k_scan<<<1, 1024, 0, stream>>>(cnt, row_start);
    k_scatter<<<5000, 256, 0, stream>>>(eidx, row_start, c2, perm);
    k_precompute<<<10000, 256, 0, stream>>>(scalars, Wa1, ba1, P1, P2);
    k_edges_sorted<<<5000, 256, 0, stream>>>(edge_vec, eidx, perm, P1, P2,
                                             W1, b1, Wa1, Wa2, ba2,
                                             attsh, srcbuf, hbuf);
    k_gather<<<20000, 256, 0, stream>>>(scalars, vectors, W2, b2, row_start,
                                        attsh, srcbuf, hbuf, (float*)d_out);
}

// Round 9
// 703.253 us; speedup vs baseline: 1.9635x; 1.1713x over previous
//
#include <hip/hip_runtime.h>

static constexpr int N_ = 40000;
static constexpr int E_ = 1280000;
static constexpr int NS = N_ * 64;      // 2,560,000 scalar elems
static constexpr int NV = N_ * 48;      // 1,920,000 vector elems

__device__ __forceinline__ float silu_f(float x) { return __fdividef(x, 1.f + __expf(-x)); }
__device__ __forceinline__ int rfl(int x) { return __builtin_amdgcn_readfirstlane(x); }

// ---- per-node attention precompute ----
// P1[n][j] = ba1[j] + sum_k s[n][k]*Wa1[k][j]      (s_i / dst part)
// P2[n][j] =          sum_k s[n][k]*Wa1[64+k][j]   (s_j / src part)
__global__ void k_precompute(const float* __restrict__ scalars, const float* __restrict__ Wa1,
                             const float* __restrict__ ba1,
                             float* __restrict__ P1, float* __restrict__ P2)
{
    int t = blockIdx.x * 256 + threadIdx.x;  // t < N*64
    int n = t >> 6, j = t & 63;
    float a1 = ba1[j];
    float a2 = 0.f;
    const float* srow = scalars + (size_t)n * 64;
#pragma unroll 8
    for (int k = 0; k < 64; k++) {
        float s = srow[k];
        a1 = fmaf(s, Wa1[k * 64 + j], a1);
        a2 = fmaf(s, Wa1[(64 + k) * 64 + j], a2);
    }
    P1[t] = a1;
    P2[t] = a2;
}

// ================= CSR build: rank + parallel scan + place (one atomic pass) =================
// r[e] = arrival rank of edge e within its dst bucket; cnt[dst] ends as the count.
__global__ void k_rank(const int* __restrict__ eidx, int* __restrict__ cnt,
                       int* __restrict__ r)
{
    int e = blockIdx.x * 256 + threadIdx.x;
    r[e] = atomicAdd(&cnt[eidx[E_ + e]], 1);
}

// 40 blocks x 1024: per-block exclusive scan (same Hillis-Steele inner loop as the
// proven round-3 k_scan chunk), block totals to bsum.
__global__ void k_scan1(const int* __restrict__ cnt, int* __restrict__ row_start,
                        int* __restrict__ bsum)
{
    __shared__ int buf[1024];
    int b = blockIdx.x, tid = threadIdx.x;
    int idx = b * 1024 + tid;
    int v = (idx < N_) ? cnt[idx] : 0;
    buf[tid] = v;
    __syncthreads();
    for (int off = 1; off < 1024; off <<= 1) {
        int t = (tid >= off) ? buf[tid - off] : 0;
        __syncthreads();
        buf[tid] += t;
        __syncthreads();
    }
    if (idx < N_) row_start[idx] = buf[tid] - v;  // exclusive within block
    if (tid == 1023) bsum[b] = buf[1023];
}

__global__ void k_scan2(const int* __restrict__ bsum, int* __restrict__ boff)
{
    if (threadIdx.x == 0) {
        int s = 0;
        for (int b = 0; b < 40; b++) { boff[b] = s; s += bsum[b]; }
    }
}

__global__ void k_scan3(const int* __restrict__ boff, int* __restrict__ row_start)
{
    int idx = blockIdx.x * 1024 + threadIdx.x;
    if (idx < N_) row_start[idx] += boff[blockIdx.x];
    if (idx == N_) row_start[N_] = E_;   // block 39 covers 39936..40959 >= N_
}

__global__ void k_place(const int* __restrict__ eidx, const int* __restrict__ row_start,
                        const int* __restrict__ r, int* __restrict__ perm)
{
    int e = blockIdx.x * 256 + threadIdx.x;
    int dst = eidx[E_ + e];
    perm[row_start[dst] + r[e]] = e;
}

// ================= edge phase (round-8 proven, unchanged) =================
__global__ __launch_bounds__(256, 2) void k_edges_sorted(
    const float* __restrict__ edge_vec, const int* __restrict__ eidx,
    const int* __restrict__ perm,
    const float* __restrict__ P1, const float* __restrict__ P2,
    const float* __restrict__ W1, const float* __restrict__ b1,
    const float* __restrict__ Wa1, const float* __restrict__ Wa2,
    const float* __restrict__ ba2,
    float4* __restrict__ attsh, int* __restrict__ srcbuf, float* __restrict__ hbuf)
{
    int i = blockIdx.x * 256 + threadIdx.x;
    int e = perm[i];
    int src = eidx[e];
    int dst = eidx[E_ + e];

    float ev0 = edge_vec[3 * e + 0];
    float ev1 = edge_vec[3 * e + 1];
    float ev2 = edge_vec[3 * e + 2];
    float d = sqrtf(fmaf(ev0, ev0, fmaf(ev1, ev1, ev2 * ev2)));
    float inv_d = __fdividef(1.f, fmaxf(d, 1e-8f));
    float cut = (d < 10.f) ? 0.5f * (__cosf(0.31415927f * d) + 1.f) : 0.f;
    float cutd = cut * inv_d;
    float sh0 = ev1 * inv_d, sh1 = ev2 * inv_d, sh2 = ev0 * inv_d;  // [uy, uz, ux]

    float g[96];
#pragma unroll
    for (int j = 0; j < 96; j++) g[j] = 0.f;
    for (int k = 0; k < 32; k++) {
        float rk = __sinf((float)(k + 1) * 0.31415927f * d) * cutd;
        const float* wa = Wa1 + (128 + k) * 64;
        const float* w1 = W1 + k * 32;
#pragma unroll
        for (int j = 0; j < 64; j++) g[j] = fmaf(rk, wa[j], g[j]);
#pragma unroll
        for (int j = 0; j < 32; j++) g[64 + j] = fmaf(rk, w1[j], g[64 + j]);
    }

    const float4* p14 = (const float4*)(P1 + (size_t)dst * 64);
    const float4* p24 = (const float4*)(P2 + (size_t)src * 64);
    float logit = ba2[0];
#pragma unroll
    for (int q = 0; q < 16; q++) {
        float4 a = p14[q];
        float4 b = p24[q];
        float aj0 = a.x + b.x + g[4 * q + 0];
        logit = fmaf(silu_f(aj0), Wa2[4 * q + 0], logit);
        float aj1 = a.y + b.y + g[4 * q + 1];
        logit = fmaf(silu_f(aj1), Wa2[4 * q + 1], logit);
        float aj2 = a.z + b.z + g[4 * q + 2];
        logit = fmaf(silu_f(aj2), Wa2[4 * q + 2], logit);
        float aj3 = a.w + b.w + g[4 * q + 3];
        logit = fmaf(silu_f(aj3), Wa2[4 * q + 3], logit);
    }
    float att = __fdividef(1.f, 1.f + __expf(-logit));

    float4* hrow4 = (float4*)(hbuf + (size_t)i * 32);
#pragma unroll
    for (int q = 0; q < 8; q++) {
        hrow4[q] = make_float4(silu_f(g[64 + 4 * q + 0] + b1[4 * q + 0]),
                               silu_f(g[64 + 4 * q + 1] + b1[4 * q + 1]),
                               silu_f(g[64 + 4 * q + 2] + b1[4 * q + 2]),
                               silu_f(g[64 + 4 * q + 3] + b1[4 * q + 3]));
    }

    attsh[i] = make_float4(att, sh0, sh1, sh2);
    srcbuf[i] = src;
}

// ================= gather (round-7 proven, unchanged) =================
__global__ __launch_bounds__(256, 4) void k_gather(
    const float* __restrict__ scalars, const float* __restrict__ vectors,
    const float* __restrict__ W2, const float* __restrict__ b2,
    const int* __restrict__ row_start,
    const float4* __restrict__ attsh, const int* __restrict__ srcbuf,
    const float* __restrict__ hbuf,
    float* __restrict__ out)
{
    int wid  = threadIdx.x >> 6;
    int lane = threadIdx.x & 63;
    int n    = blockIdx.x * 2 + (wid >> 1);
    int role = wid & 1;
    int rs = rfl(row_start[n]);
    int re = rfl(row_start[n + 1]);

    if (role == 0) {
        float wj[32];
#pragma unroll
        for (int k = 0; k < 32; k++) wj[k] = W2[k * 96 + lane];
        float bj = b2[lane];
        float acc = 0.f;
        int i = rs;
        for (; i + 2 <= re; i += 2) {
            const float* h0 = hbuf + (size_t)i * 32;
            const float* h1 = h0 + 32;
            float4 as0 = attsh[i + 0];
            float4 as1 = attsh[i + 1];
            int s0 = srcbuf[i + 0];
            int s1 = srcbuf[i + 1];
            float g0 = scalars[(size_t)s0 * 64 + lane];
            float g1 = scalars[(size_t)s1 * 64 + lane];
            float f0 = bj, f1 = bj;
#pragma unroll
            for (int k = 0; k < 32; k++) {
                f0 = fmaf(h0[k], wj[k], f0);
                f1 = fmaf(h1[k], wj[k], f1);
            }
            acc = fmaf(as0.x * g0, f0, acc);
            acc = fmaf(as1.x * g1, f1, acc);
        }
        if (i < re) {
            const float* h0 = hbuf + (size_t)i * 32;
            float4 as = attsh[i];
            int s0 = srcbuf[i];
            float f = bj;
#pragma unroll
            for (int k = 0; k < 32; k++) f = fmaf(h0[k], wj[k], f);
            acc = fmaf(as.x * scalars[(size_t)s0 * 64 + lane], f, acc);
        }
        out[(size_t)n * 64 + lane] = scalars[(size_t)n * 64 + lane] + acc;
    } else {
        int m_src = lane / 3;                 // lanes 0-47: message (m,c); 48-63: junk (unused)
        int c     = lane - 3 * m_src;
        int lsel  = (lane < 48) ? lane : 47;  // clamp to stay in-bounds for vj loads
        int col = (lane < 16) ? (64 + lane) : ((lane < 32) ? (80 + (lane - 16)) : (64 + (lane & 15)));
        float wv[32];
#pragma unroll
        for (int k = 0; k < 32; k++) wv[k] = W2[k * 96 + col];
        float bv = b2[col];
        float acc = 0.f;
        int i = rs;
        for (; i + 2 <= re; i += 2) {
            const float* h0 = hbuf + (size_t)i * 32;
            const float* h1 = h0 + 32;
            float4 as0 = attsh[i + 0];
            float4 as1 = attsh[i + 1];
            int s0 = srcbuf[i + 0];
            int s1 = srcbuf[i + 1];
            float vj0 = vectors[(size_t)s0 * 48 + lsel];
            float vj1 = vectors[(size_t)s1 * 48 + lsel];
            float fv0 = bv, fv1 = bv;
#pragma unroll
            for (int k = 0; k < 32; k++) {
                fv0 = fmaf(h0[k], wv[k], fv0);
                fv1 = fmaf(h1[k], wv[k], fv1);
            }
            float vf0 = __shfl(fv0, m_src, 64);
            float vg0 = __shfl(fv0, 16 + m_src, 64);
            float vf1 = __shfl(fv1, m_src, 64);
            float vg1 = __shfl(fv1, 16 + m_src, 64);
            float sh0c = (c == 0) ? as0.y : ((c == 1) ? as0.z : as0.w);
            float sh1c = (c == 0) ? as1.y : ((c == 1) ? as1.z : as1.w);
            acc = fmaf(as0.x, fmaf(vj0, vf0, vg0 * sh0c), acc);
            acc = fmaf(as1.x, fmaf(vj1, vf1, vg1 * sh1c), acc);
        }
        if (i < re) {
            const float* h0 = hbuf + (size_t)i * 32;
            float4 as = attsh[i];
            int s0 = srcbuf[i];
            float vjc = vectors[(size_t)s0 * 48 + lsel];
            float fv = bv;
#pragma unroll
            for (int k = 0; k < 32; k++) fv = fmaf(h0[k], wv[k], fv);
            float vf = __shfl(fv, m_src, 64);
            float vg = __shfl(fv, 16 + m_src, 64);
            float shc = (c == 0) ? as.y : ((c == 1) ? as.z : as.w);
            acc = fmaf(as.x, fmaf(vjc, vf, vg * shc), acc);
        }
        if (lane < 48)
            out[NS + (size_t)n * 48 + lane] = vectors[(size_t)n * 48 + lane] + acc;
    }
}

extern "C" void kernel_launch(void* const* d_in, const int* in_sizes, int n_in,
                              void* d_out, int out_size, void* d_ws, size_t ws_size,
                              hipStream_t stream)
{
    const float* scalars  = (const float*)d_in[0];
    const float* vectors  = (const float*)d_in[1];
    const float* edge_vec = (const float*)d_in[2];
    const float* W1  = (const float*)d_in[3];
    const float* b1  = (const float*)d_in[4];
    const float* W2  = (const float*)d_in[5];
    const float* b2  = (const float*)d_in[6];
    const float* Wa1 = (const float*)d_in[7];
    const float* ba1 = (const float*)d_in[8];
    const float* Wa2 = (const float*)d_in[9];
    const float* ba2 = (const float*)d_in[10];
    const int* eidx  = (const int*)d_in[11];

    char* wsb = (char*)d_ws;
    // round-3 proven layout: attsh | P1 | P2 | hbuf | cnt | c2 | row_start | perm | srcbuf
    // (c2 slot kept for layout stability; now holds bsum/boff for the parallel scan)
    float4* attsh = (float4*)wsb;                       // E float4      = 20.48 MB
    float*  P1    = (float*)(wsb + (size_t)E_ * 16);    // NS floats     = 10.24 MB
    float*  P2    = P1 + NS;                            // NS floats     = 10.24 MB
    float*  hbuf  = P2 + NS;                            // 32E floats    = 163.84 MB
    int* cnt       = (int*)(hbuf + (size_t)32 * E_);    // N
    int* bsum      = cnt + N_;                          // 40   (in old c2 slot)
    int* boff      = bsum + 64;                         // 40   (in old c2 slot)
    int* row_start = cnt + 2 * N_;                      // N+1
    int* perm      = row_start + N_ + 1;                // E
    int* srcbuf    = perm + E_;                         // E  (end ~215.6 MB; round 3 proved ws fits)
    // rank array lives in the hbuf region (hbuf is only written later, by k_edges_sorted)
    int* rnk       = (int*)hbuf;                        // E ints = 5.12 MB < 163.84 MB

    hipMemsetAsync(cnt, 0, (size_t)N_ * sizeof(int), stream);
    k_rank<<<5000, 256, 0, stream>>>(eidx, cnt, rnk);
    k_scan1<<<40, 1024, 0, stream>>>(cnt, row_start, bsum);
    k_scan2<<<1, 64, 0, stream>>>(bsum, boff);
    k_scan3<<<40, 1024, 0, stream>>>(boff, row_start);
    k_place<<<5000, 256, 0, stream>>>(eidx, row_start, rnk, perm);
    k_precompute<<<10000, 256, 0, stream>>>(scalars, Wa1, ba1, P1, P2);
    k_edges_sorted<<<5000, 256, 0, stream>>>(edge_vec, eidx, perm, P1, P2,
                                             W1, b1, Wa1, Wa2, ba2,
                                             attsh, srcbuf, hbuf);
    k_gather<<<20000, 256, 0, stream>>>(scalars, vectors, W2, b2, row_start,
                                        attsh, srcbuf, hbuf, (float*)d_out);
}

// Round 10
// 574.296 us; speedup vs baseline: 2.4044x; 1.2245x over previous
//
#include <hip/hip_runtime.h>

static constexpr int N_ = 40000;
static constexpr int E_ = 1280000;
static constexpr int NS = N_ * 64;      // 2,560,000 scalar elems
static constexpr int NV = N_ * 48;      // 1,920,000 vector elems

typedef _Float16 half2_t __attribute__((ext_vector_type(2)));
typedef unsigned int uint;

#if defined(__has_builtin)
#  if __has_builtin(__builtin_amdgcn_fdot2)
#    define HAVE_FDOT2 1
#  endif
#endif
#ifndef HAVE_FDOT2
#  define HAVE_FDOT2 0
#endif

__device__ __forceinline__ float silu_f(float x) { return __fdividef(x, 1.f + __expf(-x)); }
__device__ __forceinline__ int rfl(int x) { return __builtin_amdgcn_readfirstlane(x); }

// packed f16 dot: acc += h2.x*w2.x + h2.y*w2.y  (v_dot2_f32_f16, 1 inst for 2 MACs)
__device__ __forceinline__ float dot2acc(uint hp, half2_t wp, float acc) {
#if HAVE_FDOT2
    return __builtin_amdgcn_fdot2(__builtin_bit_cast(half2_t, hp), wp, acc, false);
#else
    half2_t h = __builtin_bit_cast(half2_t, hp);
    acc = fmaf((float)h.x, (float)wp.x, acc);
    return fmaf((float)h.y, (float)wp.y, acc);
#endif
}

// ---- per-node attention precompute ----
// P1[n][j] = ba1[j] + sum_k s[n][k]*Wa1[k][j]      (s_i / dst part)
// P2[n][j] =          sum_k s[n][k]*Wa1[64+k][j]   (s_j / src part)
__global__ void k_precompute(const float* __restrict__ scalars, const float* __restrict__ Wa1,
                             const float* __restrict__ ba1,
                             float* __restrict__ P1, float* __restrict__ P2)
{
    int t = blockIdx.x * 256 + threadIdx.x;  // t < N*64
    int n = t >> 6, j = t & 63;
    float a1 = ba1[j];
    float a2 = 0.f;
    const float* srow = scalars + (size_t)n * 64;
#pragma unroll 8
    for (int k = 0; k < 64; k++) {
        float s = srow[k];
        a1 = fmaf(s, Wa1[k * 64 + j], a1);
        a2 = fmaf(s, Wa1[(64 + k) * 64 + j], a2);
    }
    P1[t] = a1;
    P2[t] = a2;
}

// ================= CSR build: rank + parallel scan + place (round-9 proven) =================
__global__ void k_rank(const int* __restrict__ eidx, int* __restrict__ cnt,
                       int* __restrict__ r)
{
    int e = blockIdx.x * 256 + threadIdx.x;
    r[e] = atomicAdd(&cnt[eidx[E_ + e]], 1);
}

__global__ void k_scan1(const int* __restrict__ cnt, int* __restrict__ row_start,
                        int* __restrict__ bsum)
{
    __shared__ int buf[1024];
    int b = blockIdx.x, tid = threadIdx.x;
    int idx = b * 1024 + tid;
    int v = (idx < N_) ? cnt[idx] : 0;
    buf[tid] = v;
    __syncthreads();
    for (int off = 1; off < 1024; off <<= 1) {
        int t = (tid >= off) ? buf[tid - off] : 0;
        __syncthreads();
        buf[tid] += t;
        __syncthreads();
    }
    if (idx < N_) row_start[idx] = buf[tid] - v;  // exclusive within block
    if (tid == 1023) bsum[b] = buf[1023];
}

__global__ void k_scan2(const int* __restrict__ bsum, int* __restrict__ boff)
{
    if (threadIdx.x == 0) {
        int s = 0;
        for (int b = 0; b < 40; b++) { boff[b] = s; s += bsum[b]; }
    }
}

__global__ void k_scan3(const int* __restrict__ boff, int* __restrict__ row_start)
{
    int idx = blockIdx.x * 1024 + threadIdx.x;
    if (idx < N_) row_start[idx] += boff[blockIdx.x];
    if (idx == N_) row_start[N_] = E_;   // block 39 covers 39936..40959 >= N_
}

__global__ void k_place(const int* __restrict__ eidx, const int* __restrict__ row_start,
                        const int* __restrict__ r, int* __restrict__ perm)
{
    int e = blockIdx.x * 256 + threadIdx.x;
    int dst = eidx[E_ + e];
    perm[row_start[dst] + r[e]] = e;
}

// ================= edge phase: vs round 9, ONLY h store changes (f32 -> packed f16) =========
__global__ __launch_bounds__(256, 2) void k_edges_sorted(
    const float* __restrict__ edge_vec, const int* __restrict__ eidx,
    const int* __restrict__ perm,
    const float* __restrict__ P1, const float* __restrict__ P2,
    const float* __restrict__ W1, const float* __restrict__ b1,
    const float* __restrict__ Wa1, const float* __restrict__ Wa2,
    const float* __restrict__ ba2,
    float4* __restrict__ attsh, int* __restrict__ srcbuf, uint* __restrict__ hbufp)
{
    int i = blockIdx.x * 256 + threadIdx.x;
    int e = perm[i];
    int src = eidx[e];
    int dst = eidx[E_ + e];

    float ev0 = edge_vec[3 * e + 0];
    float ev1 = edge_vec[3 * e + 1];
    float ev2 = edge_vec[3 * e + 2];
    float d = sqrtf(fmaf(ev0, ev0, fmaf(ev1, ev1, ev2 * ev2)));
    float inv_d = __fdividef(1.f, fmaxf(d, 1e-8f));
    float cut = (d < 10.f) ? 0.5f * (__cosf(0.31415927f * d) + 1.f) : 0.f;
    float cutd = cut * inv_d;
    float sh0 = ev1 * inv_d, sh1 = ev2 * inv_d, sh2 = ev0 * inv_d;  // [uy, uz, ux]

    float g[96];
#pragma unroll
    for (int j = 0; j < 96; j++) g[j] = 0.f;
    for (int k = 0; k < 32; k++) {
        float rk = __sinf((float)(k + 1) * 0.31415927f * d) * cutd;
        const float* wa = Wa1 + (128 + k) * 64;
        const float* w1 = W1 + k * 32;
#pragma unroll
        for (int j = 0; j < 64; j++) g[j] = fmaf(rk, wa[j], g[j]);
#pragma unroll
        for (int j = 0; j < 32; j++) g[64 + j] = fmaf(rk, w1[j], g[64 + j]);
    }

    const float4* p14 = (const float4*)(P1 + (size_t)dst * 64);
    const float4* p24 = (const float4*)(P2 + (size_t)src * 64);
    float logit = ba2[0];
#pragma unroll
    for (int q = 0; q < 16; q++) {
        float4 a = p14[q];
        float4 b = p24[q];
        float aj0 = a.x + b.x + g[4 * q + 0];
        logit = fmaf(silu_f(aj0), Wa2[4 * q + 0], logit);
        float aj1 = a.y + b.y + g[4 * q + 1];
        logit = fmaf(silu_f(aj1), Wa2[4 * q + 1], logit);
        float aj2 = a.z + b.z + g[4 * q + 2];
        logit = fmaf(silu_f(aj2), Wa2[4 * q + 2], logit);
        float aj3 = a.w + b.w + g[4 * q + 3];
        logit = fmaf(silu_f(aj3), Wa2[4 * q + 3], logit);
    }
    float att = __fdividef(1.f, 1.f + __expf(-logit));

    // h = silu(g[64:96] + b1) stored as 16 packed half2 (64 B/row)
    uint hp[16];
#pragma unroll
    for (int q = 0; q < 16; q++) {
        half2_t v;
        v.x = (_Float16)silu_f(g[64 + 2 * q + 0] + b1[2 * q + 0]);
        v.y = (_Float16)silu_f(g[64 + 2 * q + 1] + b1[2 * q + 1]);
        hp[q] = __builtin_bit_cast(uint, v);
    }
    uint4* hrow4 = (uint4*)(hbufp + (size_t)i * 16);
#pragma unroll
    for (int q = 0; q < 4; q++)
        hrow4[q] = make_uint4(hp[4 * q + 0], hp[4 * q + 1], hp[4 * q + 2], hp[4 * q + 3]);

    attsh[i] = make_float4(att, sh0, sh1, sh2);
    srcbuf[i] = src;
}

// ================= gather: vs round 9, ONLY the h@W2 dots change (fdot2 on packed f16) =====
__global__ __launch_bounds__(256, 4) void k_gather(
    const float* __restrict__ scalars, const float* __restrict__ vectors,
    const float* __restrict__ W2, const float* __restrict__ b2,
    const int* __restrict__ row_start,
    const float4* __restrict__ attsh, const int* __restrict__ srcbuf,
    const uint* __restrict__ hbuf,
    float* __restrict__ out)
{
    int wid  = threadIdx.x >> 6;
    int lane = threadIdx.x & 63;
    int n    = blockIdx.x * 2 + (wid >> 1);
    int role = wid & 1;
    int rs = rfl(row_start[n]);
    int re = rfl(row_start[n + 1]);

    if (role == 0) {
        half2_t wjp[16];
#pragma unroll
        for (int q = 0; q < 16; q++) {
            half2_t w;
            w.x = (_Float16)W2[(2 * q + 0) * 96 + lane];
            w.y = (_Float16)W2[(2 * q + 1) * 96 + lane];
            wjp[q] = w;
        }
        float bj = b2[lane];
        float acc = 0.f;
        int i = rs;
        for (; i + 2 <= re; i += 2) {
            const uint* h0 = hbuf + (size_t)i * 16;
            const uint* h1 = h0 + 16;
            float4 as0 = attsh[i + 0];
            float4 as1 = attsh[i + 1];
            int s0 = srcbuf[i + 0];
            int s1 = srcbuf[i + 1];
            float g0 = scalars[(size_t)s0 * 64 + lane];
            float g1 = scalars[(size_t)s1 * 64 + lane];
            float f0 = bj, f1 = bj;
#pragma unroll
            for (int q = 0; q < 16; q++) {
                f0 = dot2acc(h0[q], wjp[q], f0);
                f1 = dot2acc(h1[q], wjp[q], f1);
            }
            acc = fmaf(as0.x * g0, f0, acc);
            acc = fmaf(as1.x * g1, f1, acc);
        }
        if (i < re) {
            const uint* h0 = hbuf + (size_t)i * 16;
            float4 as = attsh[i];
            int s0 = srcbuf[i];
            float f = bj;
#pragma unroll
            for (int q = 0; q < 16; q++) f = dot2acc(h0[q], wjp[q], f);
            acc = fmaf(as.x * scalars[(size_t)s0 * 64 + lane], f, acc);
        }
        out[(size_t)n * 64 + lane] = scalars[(size_t)n * 64 + lane] + acc;
    } else {
        int m_src = lane / 3;                 // lanes 0-47: message (m,c); 48-63: junk (unused)
        int c     = lane - 3 * m_src;
        int lsel  = (lane < 48) ? lane : 47;  // clamp to stay in-bounds for vj loads
        int col = (lane < 16) ? (64 + lane) : ((lane < 32) ? (80 + (lane - 16)) : (64 + (lane & 15)));
        half2_t wvp[16];
#pragma unroll
        for (int q = 0; q < 16; q++) {
            half2_t w;
            w.x = (_Float16)W2[(2 * q + 0) * 96 + col];
            w.y = (_Float16)W2[(2 * q + 1) * 96 + col];
            wvp[q] = w;
        }
        float bv = b2[col];
        float acc = 0.f;
        int i = rs;
        for (; i + 2 <= re; i += 2) {
            const uint* h0 = hbuf + (size_t)i * 16;
            const uint* h1 = h0 + 16;
            float4 as0 = attsh[i + 0];
            float4 as1 = attsh[i + 1];
            int s0 = srcbuf[i + 0];
            int s1 = srcbuf[i + 1];
            float vj0 = vectors[(size_t)s0 * 48 + lsel];
            float vj1 = vectors[(size_t)s1 * 48 + lsel];
            float fv0 = bv, fv1 = bv;
#pragma unroll
            for (int q = 0; q < 16; q++) {
                fv0 = dot2acc(h0[q], wvp[q], fv0);
                fv1 = dot2acc(h1[q], wvp[q], fv1);
            }
            float vf0 = __shfl(fv0, m_src, 64);
            float vg0 = __shfl(fv0, 16 + m_src, 64);
            float vf1 = __shfl(fv1, m_src, 64);
            float vg1 = __shfl(fv1, 16 + m_src, 64);
            float sh0c = (c == 0) ? as0.y : ((c == 1) ? as0.z : as0.w);
            float sh1c = (c == 0) ? as1.y : ((c == 1) ? as1.z : as1.w);
            acc = fmaf(as0.x, fmaf(vj0, vf0, vg0 * sh0c), acc);
            acc = fmaf(as1.x, fmaf(vj1, vf1, vg1 * sh1c), acc);
        }
        if (i < re) {
            const uint* h0 = hbuf + (size_t)i * 16;
            float4 as = attsh[i];
            int s0 = srcbuf[i];
            float vjc = vectors[(size_t)s0 * 48 + lsel];
            float fv = bv;
#pragma unroll
            for (int q = 0; q < 16; q++) fv = dot2acc(h0[q], wvp[q], fv);
            float vf = __shfl(fv, m_src, 64);
            float vg = __shfl(fv, 16 + m_src, 64);
            float shc = (c == 0) ? as.y : ((c == 1) ? as.z : as.w);
            acc = fmaf(as.x, fmaf(vjc, vf, vg * shc), acc);
        }
        if (lane < 48)
            out[NS + (size_t)n * 48 + lane] = vectors[(size_t)n * 48 + lane] + acc;
    }
}

extern "C" void kernel_launch(void* const* d_in, const int* in_sizes, int n_in,
                              void* d_out, int out_size, void* d_ws, size_t ws_size,
                              hipStream_t stream)
{
    const float* scalars  = (const float*)d_in[0];
    const float* vectors  = (const float*)d_in[1];
    const float* edge_vec = (const float*)d_in[2];
    const float* W1  = (const float*)d_in[3];
    const float* b1  = (const float*)d_in[4];
    const float* W2  = (const float*)d_in[5];
    const float* b2  = (const float*)d_in[6];
    const float* Wa1 = (const float*)d_in[7];
    const float* ba1 = (const float*)d_in[8];
    const float* Wa2 = (const float*)d_in[9];
    const float* ba2 = (const float*)d_in[10];
    const int* eidx  = (const int*)d_in[11];

    char* wsb = (char*)d_ws;
    // round-3 proven layout (unchanged): attsh | P1 | P2 | hbuf(region) | cnt | bsum/boff | row_start | perm | srcbuf
    // hbuf region still reserves 32E floats; packed-f16 h uses only the first 16E uints of it.
    float4* attsh = (float4*)wsb;                       // E float4      = 20.48 MB
    float*  P1    = (float*)(wsb + (size_t)E_ * 16);    // NS floats     = 10.24 MB
    float*  P2    = P1 + NS;                            // NS floats     = 10.24 MB
    float*  hbuf  = P2 + NS;                            // region: 32E floats = 163.84 MB
    int* cnt       = (int*)(hbuf + (size_t)32 * E_);    // N
    int* bsum      = cnt + N_;                          // 40
    int* boff      = bsum + 64;                         // 40
    int* row_start = cnt + 2 * N_;                      // N+1
    int* perm      = row_start + N_ + 1;                // E
    int* srcbuf    = perm + E_;                         // E  (end ~215.6 MB; round 3 proved ws fits)
    // rank array aliases the hbuf region (hbuf written later by k_edges_sorted, after k_place)
    int* rnk       = (int*)hbuf;                        // E ints = 5.12 MB

    hipMemsetAsync(cnt, 0, (size_t)N_ * sizeof(int), stream);
    k_rank<<<5000, 256, 0, stream>>>(eidx, cnt, rnk);
    k_scan1<<<40, 1024, 0, stream>>>(cnt, row_start, bsum);
    k_scan2<<<1, 64, 0, stream>>>(bsum, boff);
    k_scan3<<<40, 1024, 0, stream>>>(boff, row_start);
    k_place<<<5000, 256, 0, stream>>>(eidx, row_start, rnk, perm);
    k_precompute<<<10000, 256, 0, stream>>>(scalars, Wa1, ba1, P1, P2);
    k_edges_sorted<<<5000, 256, 0, stream>>>(edge_vec, eidx, perm, P1, P2,
                                             W1, b1, Wa1, Wa2, ba2,
                                             attsh, srcbuf, (uint*)hbuf);
    k_gather<<<20000, 256, 0, stream>>>(scalars, vectors, W2, b2, row_start,
                                        attsh, srcbuf, (const uint*)hbuf, (float*)d_out);
}

// Round 11
// 556.041 us; speedup vs baseline: 2.4833x; 1.0328x over previous
//
#include <hip/hip_runtime.h>

static constexpr int N_ = 40000;
static constexpr int E_ = 1280000;
static constexpr int NS = N_ * 64;      // 2,560,000 scalar elems
static constexpr int NV = N_ * 48;      // 1,920,000 vector elems

typedef _Float16 half2_t __attribute__((ext_vector_type(2)));
typedef unsigned int uint;

#if defined(__has_builtin)
#  if __has_builtin(__builtin_amdgcn_fdot2)
#    define HAVE_FDOT2 1
#  endif
#endif
#ifndef HAVE_FDOT2
#  define HAVE_FDOT2 0
#endif

__device__ __forceinline__ float silu_f(float x) { return __fdividef(x, 1.f + __expf(-x)); }
__device__ __forceinline__ int rfl(int x) { return __builtin_amdgcn_readfirstlane(x); }

// packed f16 dot: acc += h2.x*w2.x + h2.y*w2.y  (v_dot2_f32_f16, 1 inst for 2 MACs)
__device__ __forceinline__ float dot2acc(uint hp, half2_t wp, float acc) {
#if HAVE_FDOT2
    return __builtin_amdgcn_fdot2(__builtin_bit_cast(half2_t, hp), wp, acc, false);
#else
    half2_t h = __builtin_bit_cast(half2_t, hp);
    acc = fmaf((float)h.x, (float)wp.x, acc);
    return fmaf((float)h.y, (float)wp.y, acc);
#endif
}

// ---- per-node attention precompute ----
__global__ void k_precompute(const float* __restrict__ scalars, const float* __restrict__ Wa1,
                             const float* __restrict__ ba1,
                             float* __restrict__ P1, float* __restrict__ P2)
{
    int t = blockIdx.x * 256 + threadIdx.x;  // t < N*64
    int n = t >> 6, j = t & 63;
    float a1 = ba1[j];
    float a2 = 0.f;
    const float* srow = scalars + (size_t)n * 64;
#pragma unroll 8
    for (int k = 0; k < 64; k++) {
        float s = srow[k];
        a1 = fmaf(s, Wa1[k * 64 + j], a1);
        a2 = fmaf(s, Wa1[(64 + k) * 64 + j], a2);
    }
    P1[t] = a1;
    P2[t] = a2;
}

// ---- pack combined edge-expansion weights [Wa1_att(32x64) | W1(32x32)] as k-pair half2 ----
// tbl[j*16+q] = half2( GW[2q][j], GW[2q+1][j] ),  GW[k][j] = j<64 ? Wa1[(128+k)*64+j] : W1[k*32+(j-64)]
__global__ void k_pack(const float* __restrict__ W1, const float* __restrict__ Wa1,
                       uint* __restrict__ tbl)
{
    int t = blockIdx.x * 256 + threadIdx.x;   // 1536 = 96*16
    if (t >= 1536) return;
    int j = t >> 4, q = t & 15;
    int k0 = 2 * q, k1 = 2 * q + 1;
    float a = (j < 64) ? Wa1[(128 + k0) * 64 + j] : W1[k0 * 32 + (j - 64)];
    float b = (j < 64) ? Wa1[(128 + k1) * 64 + j] : W1[k1 * 32 + (j - 64)];
    half2_t v; v.x = (_Float16)a; v.y = (_Float16)b;
    tbl[t] = __builtin_bit_cast(uint, v);
}

// ================= CSR build: rank + parallel scan + place (round-9 proven) =================
__global__ void k_rank(const int* __restrict__ eidx, int* __restrict__ cnt,
                       int* __restrict__ r)
{
    int e = blockIdx.x * 256 + threadIdx.x;
    r[e] = atomicAdd(&cnt[eidx[E_ + e]], 1);
}

__global__ void k_scan1(const int* __restrict__ cnt, int* __restrict__ row_start,
                        int* __restrict__ bsum)
{
    __shared__ int buf[1024];
    int b = blockIdx.x, tid = threadIdx.x;
    int idx = b * 1024 + tid;
    int v = (idx < N_) ? cnt[idx] : 0;
    buf[tid] = v;
    __syncthreads();
    for (int off = 1; off < 1024; off <<= 1) {
        int t = (tid >= off) ? buf[tid - off] : 0;
        __syncthreads();
        buf[tid] += t;
        __syncthreads();
    }
    if (idx < N_) row_start[idx] = buf[tid] - v;  // exclusive within block
    if (tid == 1023) bsum[b] = buf[1023];
}

__global__ void k_scan2(const int* __restrict__ bsum, int* __restrict__ boff)
{
    if (threadIdx.x == 0) {
        int s = 0;
        for (int b = 0; b < 40; b++) { boff[b] = s; s += bsum[b]; }
    }
}

__global__ void k_scan3(const int* __restrict__ boff, int* __restrict__ row_start)
{
    int idx = blockIdx.x * 1024 + threadIdx.x;
    if (idx < N_) row_start[idx] += boff[blockIdx.x];
    if (idx == N_) row_start[N_] = E_;   // block 39 covers 39936..40959 >= N_
}

__global__ void k_place(const int* __restrict__ eidx, const int* __restrict__ row_start,
                        const int* __restrict__ r, int* __restrict__ perm)
{
    int e = blockIdx.x * 256 + threadIdx.x;
    int dst = eidx[E_ + e];
    perm[row_start[dst] + r[e]] = e;
}

// ================= edge phase: vs round 10, ONLY g-expansion changes (fdot2 on packed rbf) ====
__global__ __launch_bounds__(256, 2) void k_edges_sorted(
    const float* __restrict__ edge_vec, const int* __restrict__ eidx,
    const int* __restrict__ perm,
    const float* __restrict__ P1, const float* __restrict__ P2,
    const uint* __restrict__ tbl, const float* __restrict__ b1,
    const float* __restrict__ Wa2, const float* __restrict__ ba2,
    float4* __restrict__ attsh, int* __restrict__ srcbuf, uint* __restrict__ hbufp)
{
    int i = blockIdx.x * 256 + threadIdx.x;
    int e = perm[i];
    int src = eidx[e];
    int dst = eidx[E_ + e];

    float ev0 = edge_vec[3 * e + 0];
    float ev1 = edge_vec[3 * e + 1];
    float ev2 = edge_vec[3 * e + 2];
    float d = sqrtf(fmaf(ev0, ev0, fmaf(ev1, ev1, ev2 * ev2)));
    float inv_d = __fdividef(1.f, fmaxf(d, 1e-8f));
    float cut = (d < 10.f) ? 0.5f * (__cosf(0.31415927f * d) + 1.f) : 0.f;
    float cutd = cut * inv_d;
    float sh0 = ev1 * inv_d, sh1 = ev2 * inv_d, sh2 = ev0 * inv_d;  // [uy, uz, ux]

    // rbf basis, packed to half2
    uint rbf2[16];
#pragma unroll
    for (int q = 0; q < 16; q++) {
        float r0 = __sinf((float)(2 * q + 1) * 0.31415927f * d) * cutd;
        float r1 = __sinf((float)(2 * q + 2) * 0.31415927f * d) * cutd;
        half2_t v; v.x = (_Float16)r0; v.y = (_Float16)r1;
        rbf2[q] = __builtin_bit_cast(uint, v);
    }

    // g[0:64] = rbf @ Wa1[128:160] (att rows); g[64:96] = rbf @ W1 (pre-h) — via fdot2
    float g[96];
#pragma unroll
    for (int j = 0; j < 96; j++) {
        float acc = 0.f;
        const uint* tj = tbl + j * 16;
#pragma unroll
        for (int q = 0; q < 16; q++)
            acc = dot2acc(rbf2[q], __builtin_bit_cast(half2_t, tj[q]), acc);
        g[j] = acc;
    }

    const float4* p14 = (const float4*)(P1 + (size_t)dst * 64);
    const float4* p24 = (const float4*)(P2 + (size_t)src * 64);
    float logit = ba2[0];
#pragma unroll
    for (int q = 0; q < 16; q++) {
        float4 a = p14[q];
        float4 b = p24[q];
        float aj0 = a.x + b.x + g[4 * q + 0];
        logit = fmaf(silu_f(aj0), Wa2[4 * q + 0], logit);
        float aj1 = a.y + b.y + g[4 * q + 1];
        logit = fmaf(silu_f(aj1), Wa2[4 * q + 1], logit);
        float aj2 = a.z + b.z + g[4 * q + 2];
        logit = fmaf(silu_f(aj2), Wa2[4 * q + 2], logit);
        float aj3 = a.w + b.w + g[4 * q + 3];
        logit = fmaf(silu_f(aj3), Wa2[4 * q + 3], logit);
    }
    float att = __fdividef(1.f, 1.f + __expf(-logit));

    // h = silu(g[64:96] + b1) stored as 16 packed half2 (64 B/row)
    uint hp[16];
#pragma unroll
    for (int q = 0; q < 16; q++) {
        half2_t v;
        v.x = (_Float16)silu_f(g[64 + 2 * q + 0] + b1[2 * q + 0]);
        v.y = (_Float16)silu_f(g[64 + 2 * q + 1] + b1[2 * q + 1]);
        hp[q] = __builtin_bit_cast(uint, v);
    }
    uint4* hrow4 = (uint4*)(hbufp + (size_t)i * 16);
#pragma unroll
    for (int q = 0; q < 4; q++)
        hrow4[q] = make_uint4(hp[4 * q + 0], hp[4 * q + 1], hp[4 * q + 2], hp[4 * q + 3]);

    attsh[i] = make_float4(att, sh0, sh1, sh2);
    srcbuf[i] = src;
}

// ================= gather (round-10 proven, unchanged) =================
__global__ __launch_bounds__(256, 4) void k_gather(
    const float* __restrict__ scalars, const float* __restrict__ vectors,
    const float* __restrict__ W2, const float* __restrict__ b2,
    const int* __restrict__ row_start,
    const float4* __restrict__ attsh, const int* __restrict__ srcbuf,
    const uint* __restrict__ hbuf,
    float* __restrict__ out)
{
    int wid  = threadIdx.x >> 6;
    int lane = threadIdx.x & 63;
    int n    = blockIdx.x * 2 + (wid >> 1);
    int role = wid & 1;
    int rs = rfl(row_start[n]);
    int re = rfl(row_start[n + 1]);

    if (role == 0) {
        half2_t wjp[16];
#pragma unroll
        for (int q = 0; q < 16; q++) {
            half2_t w;
            w.x = (_Float16)W2[(2 * q + 0) * 96 + lane];
            w.y = (_Float16)W2[(2 * q + 1) * 96 + lane];
            wjp[q] = w;
        }
        float bj = b2[lane];
        float acc = 0.f;
        int i = rs;
        for (; i + 2 <= re; i += 2) {
            const uint* h0 = hbuf + (size_t)i * 16;
            const uint* h1 = h0 + 16;
            float4 as0 = attsh[i + 0];
            float4 as1 = attsh[i + 1];
            int s0 = srcbuf[i + 0];
            int s1 = srcbuf[i + 1];
            float g0 = scalars[(size_t)s0 * 64 + lane];
            float g1 = scalars[(size_t)s1 * 64 + lane];
            float f0 = bj, f1 = bj;
#pragma unroll
            for (int q = 0; q < 16; q++) {
                f0 = dot2acc(h0[q], wjp[q], f0);
                f1 = dot2acc(h1[q], wjp[q], f1);
            }
            acc = fmaf(as0.x * g0, f0, acc);
            acc = fmaf(as1.x * g1, f1, acc);
        }
        if (i < re) {
            const uint* h0 = hbuf + (size_t)i * 16;
            float4 as = attsh[i];
            int s0 = srcbuf[i];
            float f = bj;
#pragma unroll
            for (int q = 0; q < 16; q++) f = dot2acc(h0[q], wjp[q], f);
            acc = fmaf(as.x * scalars[(size_t)s0 * 64 + lane], f, acc);
        }
        out[(size_t)n * 64 + lane] = scalars[(size_t)n * 64 + lane] + acc;
    } else {
        int m_src = lane / 3;                 // lanes 0-47: message (m,c); 48-63: junk (unused)
        int c     = lane - 3 * m_src;
        int lsel  = (lane < 48) ? lane : 47;  // clamp to stay in-bounds for vj loads
        int col = (lane < 16) ? (64 + lane) : ((lane < 32) ? (80 + (lane - 16)) : (64 + (lane & 15)));
        half2_t wvp[16];
#pragma unroll
        for (int q = 0; q < 16; q++) {
            half2_t w;
            w.x = (_Float16)W2[(2 * q + 0) * 96 + col];
            w.y = (_Float16)W2[(2 * q + 1) * 96 + col];
            wvp[q] = w;
        }
        float bv = b2[col];
        float acc = 0.f;
        int i = rs;
        for (; i + 2 <= re; i += 2) {
            const uint* h0 = hbuf + (size_t)i * 16;
            const uint* h1 = h0 + 16;
            float4 as0 = attsh[i + 0];
            float4 as1 = attsh[i + 1];
            int s0 = srcbuf[i + 0];
            int s1 = srcbuf[i + 1];
            float vj0 = vectors[(size_t)s0 * 48 + lsel];
            float vj1 = vectors[(size_t)s1 * 48 + lsel];
            float fv0 = bv, fv1 = bv;
#pragma unroll
            for (int q = 0; q < 16; q++) {
                fv0 = dot2acc(h0[q], wvp[q], fv0);
                fv1 = dot2acc(h1[q], wvp[q], fv1);
            }
            float vf0 = __shfl(fv0, m_src, 64);
            float vg0 = __shfl(fv0, 16 + m_src, 64);
            float vf1 = __shfl(fv1, m_src, 64);
            float vg1 = __shfl(fv1, 16 + m_src, 64);
            float sh0c = (c == 0) ? as0.y : ((c == 1) ? as0.z : as0.w);
            float sh1c = (c == 0) ? as1.y : ((c == 1) ? as1.z : as1.w);
            acc = fmaf(as0.x, fmaf(vj0, vf0, vg0 * sh0c), acc);
            acc = fmaf(as1.x, fmaf(vj1, vf1, vg1 * sh1c), acc);
        }
        if (i < re) {
            const uint* h0 = hbuf + (size_t)i * 16;
            float4 as = attsh[i];
            int s0 = srcbuf[i];
            float vjc = vectors[(size_t)s0 * 48 + lsel];
            float fv = bv;
#pragma unroll
            for (int q = 0; q < 16; q++) fv = dot2acc(h0[q], wvp[q], fv);
            float vf = __shfl(fv, m_src, 64);
            float vg = __shfl(fv, 16 + m_src, 64);
            float shc = (c == 0) ? as.y : ((c == 1) ? as.z : as.w);
            acc = fmaf(as.x, fmaf(vjc, vf, vg * shc), acc);
        }
        if (lane < 48)
            out[NS + (size_t)n * 48 + lane] = vectors[(size_t)n * 48 + lane] + acc;
    }
}

extern "C" void kernel_launch(void* const* d_in, const int* in_sizes, int n_in,
                              void* d_out, int out_size, void* d_ws, size_t ws_size,
                              hipStream_t stream)
{
    const float* scalars  = (const float*)d_in[0];
    const float* vectors  = (const float*)d_in[1];
    const float* edge_vec = (const float*)d_in[2];
    const float* W1  = (const float*)d_in[3];
    const float* b1  = (const float*)d_in[4];
    const float* W2  = (const float*)d_in[5];
    const float* b2  = (const float*)d_in[6];
    const float* Wa1 = (const float*)d_in[7];
    const float* ba1 = (const float*)d_in[8];
    const float* Wa2 = (const float*)d_in[9];
    const float* ba2 = (const float*)d_in[10];
    const int* eidx  = (const int*)d_in[11];

    char* wsb = (char*)d_ws;
    // round-3 proven layout (unchanged footprint): attsh | P1 | P2 | hbuf(region) | ints
    float4* attsh = (float4*)wsb;                       // E float4      = 20.48 MB
    float*  P1    = (float*)(wsb + (size_t)E_ * 16);    // NS floats     = 10.24 MB
    float*  P2    = P1 + NS;                            // NS floats     = 10.24 MB
    float*  hbuf  = P2 + NS;                            // region: 32E floats = 163.84 MB
    int* cnt       = (int*)(hbuf + (size_t)32 * E_);    // N
    int* bsum      = cnt + N_;                          // 40
    int* boff      = bsum + 64;                         // 40
    int* row_start = cnt + 2 * N_;                      // N+1
    int* perm      = row_start + N_ + 1;                // E
    int* srcbuf    = perm + E_;                         // E  (end ~215.6 MB; proven fits)
    // aliases inside the hbuf region (packed-f16 h uses only the first 16E uints):
    int*  rnk = (int*)hbuf;                             // E ints (dead after k_place)
    uint* tbl = (uint*)hbuf + (size_t)16 * E_;          // 1536 uints (in hbuf region tail)

    hipMemsetAsync(cnt, 0, (size_t)N_ * sizeof(int), stream);
    k_pack<<<6, 256, 0, stream>>>(W1, Wa1, tbl);
    k_rank<<<5000, 256, 0, stream>>>(eidx, cnt, rnk);
    k_scan1<<<40, 1024, 0, stream>>>(cnt, row_start, bsum);
    k_scan2<<<1, 64, 0, stream>>>(bsum, boff);
    k_scan3<<<40, 1024, 0, stream>>>(boff, row_start);
    k_place<<<5000, 256, 0, stream>>>(eidx, row_start, rnk, perm);
    k_precompute<<<10000, 256, 0, stream>>>(scalars, Wa1, ba1, P1, P2);
    k_edges_sorted<<<5000, 256, 0, stream>>>(edge_vec, eidx, perm, P1, P2,
                                             tbl, b1, Wa2, ba2,
                                             attsh, srcbuf, (uint*)hbuf);
    k_gather<<<20000, 256, 0, stream>>>(scalars, vectors, W2, b2, row_start,
                                        attsh, srcbuf, (const uint*)hbuf, (float*)d_out);
}

// Round 12
// 523.019 us; speedup vs baseline: 2.6401x; 1.0631x over previous
//
#include <hip/hip_runtime.h>

static constexpr int N_ = 40000;
static constexpr int E_ = 1280000;
static constexpr int NS = N_ * 64;      // 2,560,000 scalar elems
static constexpr int NV = N_ * 48;      // 1,920,000 vector elems

typedef _Float16 half2_t __attribute__((ext_vector_type(2)));
typedef _Float16 half8_t __attribute__((ext_vector_type(8)));
typedef float float4_t __attribute__((ext_vector_type(4)));
typedef unsigned int uint;

#if defined(__has_builtin)
#  if __has_builtin(__builtin_amdgcn_fdot2)
#    define HAVE_FDOT2 1
#  endif
#endif
#ifndef HAVE_FDOT2
#  define HAVE_FDOT2 0
#endif

__device__ __forceinline__ float silu_f(float x) { return __fdividef(x, 1.f + __expf(-x)); }
__device__ __forceinline__ int rfl(int x) { return __builtin_amdgcn_readfirstlane(x); }

// packed f16 dot: acc += h2.x*w2.x + h2.y*w2.y  (v_dot2_f32_f16, 1 inst for 2 MACs)
__device__ __forceinline__ float dot2acc(uint hp, half2_t wp, float acc) {
#if HAVE_FDOT2
    return __builtin_amdgcn_fdot2(__builtin_bit_cast(half2_t, hp), wp, acc, false);
#else
    half2_t h = __builtin_bit_cast(half2_t, hp);
    acc = fmaf((float)h.x, (float)wp.x, acc);
    return fmaf((float)h.y, (float)wp.y, acc);
#endif
}

// ---- per-node attention precompute ----
__global__ void k_precompute(const float* __restrict__ scalars, const float* __restrict__ Wa1,
                             const float* __restrict__ ba1,
                             float* __restrict__ P1, float* __restrict__ P2)
{
    int t = blockIdx.x * 256 + threadIdx.x;  // t < N*64
    int n = t >> 6, j = t & 63;
    float a1 = ba1[j];
    float a2 = 0.f;
    const float* srow = scalars + (size_t)n * 64;
#pragma unroll 8
    for (int k = 0; k < 64; k++) {
        float s = srow[k];
        a1 = fmaf(s, Wa1[k * 64 + j], a1);
        a2 = fmaf(s, Wa1[(64 + k) * 64 + j], a2);
    }
    P1[t] = a1;
    P2[t] = a2;
}

// ---- pack combined edge-expansion weights [Wa1_att(32x64) | W1(32x32)] as k-pair half2 ----
// tbl[j*16+q] = half2( GW[2q][j], GW[2q+1][j] )
__global__ void k_pack(const float* __restrict__ W1, const float* __restrict__ Wa1,
                       uint* __restrict__ tbl)
{
    int t = blockIdx.x * 256 + threadIdx.x;   // 1536 = 96*16
    if (t >= 1536) return;
    int j = t >> 4, q = t & 15;
    int k0 = 2 * q, k1 = 2 * q + 1;
    float a = (j < 64) ? Wa1[(128 + k0) * 64 + j] : W1[k0 * 32 + (j - 64)];
    float b = (j < 64) ? Wa1[(128 + k1) * 64 + j] : W1[k1 * 32 + (j - 64)];
    half2_t v; v.x = (_Float16)a; v.y = (_Float16)b;
    tbl[t] = __builtin_bit_cast(uint, v);
}

// ================= CSR build: rank + parallel scan + place (round-9 proven) =================
__global__ void k_rank(const int* __restrict__ eidx, int* __restrict__ cnt,
                       int* __restrict__ r)
{
    int e = blockIdx.x * 256 + threadIdx.x;
    r[e] = atomicAdd(&cnt[eidx[E_ + e]], 1);
}

__global__ void k_scan1(const int* __restrict__ cnt, int* __restrict__ row_start,
                        int* __restrict__ bsum)
{
    __shared__ int buf[1024];
    int b = blockIdx.x, tid = threadIdx.x;
    int idx = b * 1024 + tid;
    int v = (idx < N_) ? cnt[idx] : 0;
    buf[tid] = v;
    __syncthreads();
    for (int off = 1; off < 1024; off <<= 1) {
        int t = (tid >= off) ? buf[tid - off] : 0;
        __syncthreads();
        buf[tid] += t;
        __syncthreads();
    }
    if (idx < N_) row_start[idx] = buf[tid] - v;  // exclusive within block
    if (tid == 1023) bsum[b] = buf[1023];
}

__global__ void k_scan2(const int* __restrict__ bsum, int* __restrict__ boff)
{
    if (threadIdx.x == 0) {
        int s = 0;
        for (int b = 0; b < 40; b++) { boff[b] = s; s += bsum[b]; }
    }
}

__global__ void k_scan3(const int* __restrict__ boff, int* __restrict__ row_start)
{
    int idx = blockIdx.x * 1024 + threadIdx.x;
    if (idx < N_) row_start[idx] += boff[blockIdx.x];
    if (idx == N_) row_start[N_] = E_;   // block 39 covers 39936..40959 >= N_
}

__global__ void k_place(const int* __restrict__ eidx, const int* __restrict__ row_start,
                        const int* __restrict__ r, int* __restrict__ perm)
{
    int e = blockIdx.x * 256 + threadIdx.x;
    int dst = eidx[E_ + e];
    perm[row_start[dst] + r[e]] = e;
}

// ================= edge phase: vs round 11, ONLY g-expansion changes (MFMA 16x16x32 f16) =====
// Per wave: rbf(64x32) @ GW(32x96) as 4 M-tiles x 6 N-tiles of v_mfma_f32_16x16x32_f16.
// rbf staged in per-wave LDS (A layout: m=lane&15, k=quad*8+j); B preloaded from tbl
// (n=lane&15, k=quad*8+j); D (col=lane&15, row=quad*4+reg) written as f16 to a per-wave
// LDS g-tile (row stride 98 halves = 196 B, breaks stride-96 bank aliasing). rbf region
// overlays the g region head (dead once A-frags are in VGPRs; barrier-fenced).
__global__ __launch_bounds__(256, 3) void k_edges_sorted(
    const float* __restrict__ edge_vec, const int* __restrict__ eidx,
    const int* __restrict__ perm,
    const float* __restrict__ P1, const float* __restrict__ P2,
    const uint* __restrict__ tbl, const float* __restrict__ b1,
    const float* __restrict__ Wa2, const float* __restrict__ ba2,
    float4* __restrict__ attsh, int* __restrict__ srcbuf, uint* __restrict__ hbufp)
{
    __shared__ char lds_raw[4 * 12544];          // 50176 B: 4 waves x (64 edges x 196 B)
    int tid = threadIdx.x;
    int wid = tid >> 6, lane = tid & 63;
    char* wbase = lds_raw + wid * 12544;
    int bl = lane & 15, bq = lane >> 4;

    int i = blockIdx.x * 256 + tid;
    int e = perm[i];
    int src = eidx[e];
    int dst = eidx[E_ + e];

    float ev0 = edge_vec[3 * e + 0];
    float ev1 = edge_vec[3 * e + 1];
    float ev2 = edge_vec[3 * e + 2];
    float d = sqrtf(fmaf(ev0, ev0, fmaf(ev1, ev1, ev2 * ev2)));
    float inv_d = __fdividef(1.f, fmaxf(d, 1e-8f));
    float cut = (d < 10.f) ? 0.5f * (__cosf(0.31415927f * d) + 1.f) : 0.f;
    float cutd = cut * inv_d;
    float sh0 = ev1 * inv_d, sh1 = ev2 * inv_d, sh2 = ev0 * inv_d;  // [uy, uz, ux]

    // rbf basis, packed to half2, staged to LDS (this thread's edge_loc == lane)
    uint rbf2[16];
#pragma unroll
    for (int q = 0; q < 16; q++) {
        float r0 = __sinf((float)(2 * q + 1) * 0.31415927f * d) * cutd;
        float r1 = __sinf((float)(2 * q + 2) * 0.31415927f * d) * cutd;
        half2_t v; v.x = (_Float16)r0; v.y = (_Float16)r1;
        rbf2[q] = __builtin_bit_cast(uint, v);
    }
    {
        uint4* rw = (uint4*)(wbase + lane * 64);
        rw[0] = make_uint4(rbf2[0], rbf2[1], rbf2[2], rbf2[3]);
        rw[1] = make_uint4(rbf2[4], rbf2[5], rbf2[6], rbf2[7]);
        rw[2] = make_uint4(rbf2[8], rbf2[9], rbf2[10], rbf2[11]);
        rw[3] = make_uint4(rbf2[12], rbf2[13], rbf2[14], rbf2[15]);
    }

    // B fragments: lane covers col n = 16u + bl, k-halves quad*8..+7 -> tbl[n*16 + bq*4 ..+3]
    uint4 bfr[6];
#pragma unroll
    for (int u = 0; u < 6; u++)
        bfr[u] = *(const uint4*)(tbl + (u * 16 + bl) * 16 + bq * 4);

    __syncthreads();   // rbf staged for all waves

    uint4 afr[4];
#pragma unroll
    for (int t = 0; t < 4; t++)
        afr[t] = *(const uint4*)(wbase + (t * 16 + bl) * 64 + bq * 16);

    __syncthreads();   // A-frags in VGPRs everywhere; rbf region now dead -> g may overwrite

    _Float16* gtile = (_Float16*)wbase;          // [edge_loc][col], row stride 98 halves
#pragma unroll
    for (int t = 0; t < 4; t++) {
        half8_t av = __builtin_bit_cast(half8_t, afr[t]);
        int eb = t * 16 + bq * 4;
#pragma unroll
        for (int u = 0; u < 6; u++) {
            float4_t dd = __builtin_amdgcn_mfma_f32_16x16x32_f16(
                av, __builtin_bit_cast(half8_t, bfr[u]), (float4_t)(0.f), 0, 0, 0);
            int col = u * 16 + bl;
            gtile[(eb + 0) * 98 + col] = (_Float16)dd[0];
            gtile[(eb + 1) * 98 + col] = (_Float16)dd[1];
            gtile[(eb + 2) * 98 + col] = (_Float16)dd[2];
            gtile[(eb + 3) * 98 + col] = (_Float16)dd[3];
        }
    }

    __syncthreads();   // g-tile complete for all waves

    const uint* grow = (const uint*)(wbase + (size_t)lane * 196);  // this edge's g row

    const float4* p14 = (const float4*)(P1 + (size_t)dst * 64);
    const float4* p24 = (const float4*)(P2 + (size_t)src * 64);
    float logit = ba2[0];
#pragma unroll
    for (int q = 0; q < 16; q++) {
        float4 a = p14[q];
        float4 b = p24[q];
        half2_t g01 = __builtin_bit_cast(half2_t, grow[2 * q + 0]);
        half2_t g23 = __builtin_bit_cast(half2_t, grow[2 * q + 1]);
        float aj0 = a.x + b.x + (float)g01.x;
        logit = fmaf(silu_f(aj0), Wa2[4 * q + 0], logit);
        float aj1 = a.y + b.y + (float)g01.y;
        logit = fmaf(silu_f(aj1), Wa2[4 * q + 1], logit);
        float aj2 = a.z + b.z + (float)g23.x;
        logit = fmaf(silu_f(aj2), Wa2[4 * q + 2], logit);
        float aj3 = a.w + b.w + (float)g23.y;
        logit = fmaf(silu_f(aj3), Wa2[4 * q + 3], logit);
    }
    float att = __fdividef(1.f, 1.f + __expf(-logit));

    // h = silu(g[64:96] + b1) stored as 16 packed half2 (64 B/row)
    uint hp[16];
#pragma unroll
    for (int q = 0; q < 16; q++) {
        half2_t gg = __builtin_bit_cast(half2_t, grow[32 + q]);  // g[64+2q], g[64+2q+1]
        half2_t v;
        v.x = (_Float16)silu_f((float)gg.x + b1[2 * q + 0]);
        v.y = (_Float16)silu_f((float)gg.y + b1[2 * q + 1]);
        hp[q] = __builtin_bit_cast(uint, v);
    }
    uint4* hrow4 = (uint4*)(hbufp + (size_t)i * 16);
#pragma unroll
    for (int q = 0; q < 4; q++)
        hrow4[q] = make_uint4(hp[4 * q + 0], hp[4 * q + 1], hp[4 * q + 2], hp[4 * q + 3]);

    attsh[i] = make_float4(att, sh0, sh1, sh2);
    srcbuf[i] = src;
}

// ================= gather (round-10 proven, unchanged) =================
__global__ __launch_bounds__(256, 4) void k_gather(
    const float* __restrict__ scalars, const float* __restrict__ vectors,
    const float* __restrict__ W2, const float* __restrict__ b2,
    const int* __restrict__ row_start,
    const float4* __restrict__ attsh, const int* __restrict__ srcbuf,
    const uint* __restrict__ hbuf,
    float* __restrict__ out)
{
    int wid  = threadIdx.x >> 6;
    int lane = threadIdx.x & 63;
    int n    = blockIdx.x * 2 + (wid >> 1);
    int role = wid & 1;
    int rs = rfl(row_start[n]);
    int re = rfl(row_start[n + 1]);

    if (role == 0) {
        half2_t wjp[16];
#pragma unroll
        for (int q = 0; q < 16; q++) {
            half2_t w;
            w.x = (_Float16)W2[(2 * q + 0) * 96 + lane];
            w.y = (_Float16)W2[(2 * q + 1) * 96 + lane];
            wjp[q] = w;
        }
        float bj = b2[lane];
        float acc = 0.f;
        int i = rs;
        for (; i + 2 <= re; i += 2) {
            const uint* h0 = hbuf + (size_t)i * 16;
            const uint* h1 = h0 + 16;
            float4 as0 = attsh[i + 0];
            float4 as1 = attsh[i + 1];
            int s0 = srcbuf[i + 0];
            int s1 = srcbuf[i + 1];
            float g0 = scalars[(size_t)s0 * 64 + lane];
            float g1 = scalars[(size_t)s1 * 64 + lane];
            float f0 = bj, f1 = bj;
#pragma unroll
            for (int q = 0; q < 16; q++) {
                f0 = dot2acc(h0[q], wjp[q], f0);
                f1 = dot2acc(h1[q], wjp[q], f1);
            }
            acc = fmaf(as0.x * g0, f0, acc);
            acc = fmaf(as1.x * g1, f1, acc);
        }
        if (i < re) {
            const uint* h0 = hbuf + (size_t)i * 16;
            float4 as = attsh[i];
            int s0 = srcbuf[i];
            float f = bj;
#pragma unroll
            for (int q = 0; q < 16; q++) f = dot2acc(h0[q], wjp[q], f);
            acc = fmaf(as.x * scalars[(size_t)s0 * 64 + lane], f, acc);
        }
        out[(size_t)n * 64 + lane] = scalars[(size_t)n * 64 + lane] + acc;
    } else {
        int m_src = lane / 3;                 // lanes 0-47: message (m,c); 48-63: junk (unused)
        int c     = lane - 3 * m_src;
        int lsel  = (lane < 48) ? lane : 47;  // clamp to stay in-bounds for vj loads
        int col = (lane < 16) ? (64 + lane) : ((lane < 32) ? (80 + (lane - 16)) : (64 + (lane & 15)));
        half2_t wvp[16];
#pragma unroll
        for (int q = 0; q < 16; q++) {
            half2_t w;
            w.x = (_Float16)W2[(2 * q + 0) * 96 + col];
            w.y = (_Float16)W2[(2 * q + 1) * 96 + col];
            wvp[q] = w;
        }
        float bv = b2[col];
        float acc = 0.f;
        int i = rs;
        for (; i + 2 <= re; i += 2) {
            const uint* h0 = hbuf + (size_t)i * 16;
            const uint* h1 = h0 + 16;
            float4 as0 = attsh[i + 0];
            float4 as1 = attsh[i + 1];
            int s0 = srcbuf[i + 0];
            int s1 = srcbuf[i + 1];
            float vj0 = vectors[(size_t)s0 * 48 + lsel];
            float vj1 = vectors[(size_t)s1 * 48 + lsel];
            float fv0 = bv, fv1 = bv;
#pragma unroll
            for (int q = 0; q < 16; q++) {
                fv0 = dot2acc(h0[q], wvp[q], fv0);
                fv1 = dot2acc(h1[q], wvp[q], fv1);
            }
            float vf0 = __shfl(fv0, m_src, 64);
            float vg0 = __shfl(fv0, 16 + m_src, 64);
            float vf1 = __shfl(fv1, m_src, 64);
            float vg1 = __shfl(fv1, 16 + m_src, 64);
            float sh0c = (c == 0) ? as0.y : ((c == 1) ? as0.z : as0.w);
            float sh1c = (c == 0) ? as1.y : ((c == 1) ? as1.z : as1.w);
            acc = fmaf(as0.x, fmaf(vj0, vf0, vg0 * sh0c), acc);
            acc = fmaf(as1.x, fmaf(vj1, vf1, vg1 * sh1c), acc);
        }
        if (i < re) {
            const uint* h0 = hbuf + (size_t)i * 16;
            float4 as = attsh[i];
            int s0 = srcbuf[i];
            float vjc = vectors[(size_t)s0 * 48 + lsel];
            float fv = bv;
#pragma unroll
            for (int q = 0; q < 16; q++) fv = dot2acc(h0[q], wvp[q], fv);
            float vf = __shfl(fv, m_src, 64);
            float vg = __shfl(fv, 16 + m_src, 64);
            float shc = (c == 0) ? as.y : ((c == 1) ? as.z : as.w);
            acc = fmaf(as.x, fmaf(vjc, vf, vg * shc), acc);
        }
        if (lane < 48)
            out[NS + (size_t)n * 48 + lane] = vectors[(size_t)n * 48 + lane] + acc;
    }
}

extern "C" void kernel_launch(void* const* d_in, const int* in_sizes, int n_in,
                              void* d_out, int out_size, void* d_ws, size_t ws_size,
                              hipStream_t stream)
{
    const float* scalars  = (const float*)d_in[0];
    const float* vectors  = (const float*)d_in[1];
    const float* edge_vec = (const float*)d_in[2];
    const float* W1  = (const float*)d_in[3];
    const float* b1  = (const float*)d_in[4];
    const float* W2  = (const float*)d_in[5];
    const float* b2  = (const float*)d_in[6];
    const float* Wa1 = (const float*)d_in[7];
    const float* ba1 = (const float*)d_in[8];
    const float* Wa2 = (const float*)d_in[9];
    const float* ba2 = (const float*)d_in[10];
    const int* eidx  = (const int*)d_in[11];

    char* wsb = (char*)d_ws;
    // proven layout (unchanged footprint): attsh | P1 | P2 | hbuf(region) | ints
    float4* attsh = (float4*)wsb;                       // E float4      = 20.48 MB
    float*  P1    = (float*)(wsb + (size_t)E_ * 16);    // NS floats     = 10.24 MB
    float*  P2    = P1 + NS;                            // NS floats     = 10.24 MB
    float*  hbuf  = P2 + NS;                            // region: 32E floats = 163.84 MB
    int* cnt       = (int*)(hbuf + (size_t)32 * E_);    // N
    int* bsum      = cnt + N_;                          // 40
    int* boff      = bsum + 64;                         // 40
    int* row_start = cnt + 2 * N_;                      // N+1
    int* perm      = row_start + N_ + 1;                // E
    int* srcbuf    = perm + E_;                         // E  (end ~215.6 MB; proven fits)
    // aliases inside the hbuf region (packed-f16 h uses only the first 16E uints):
    int*  rnk = (int*)hbuf;                             // E ints (dead after k_place)
    uint* tbl = (uint*)hbuf + (size_t)16 * E_;          // 1536 uints (hbuf region tail)

    hipMemsetAsync(cnt, 0, (size_t)N_ * sizeof(int), stream);
    k_pack<<<6, 256, 0, stream>>>(W1, Wa1, tbl);
    k_rank<<<5000, 256, 0, stream>>>(eidx, cnt, rnk);
    k_scan1<<<40, 1024, 0, stream>>>(cnt, row_start, bsum);
    k_scan2<<<1, 64, 0, stream>>>(bsum, boff);
    k_scan3<<<40, 1024, 0, stream>>>(boff, row_start);
    k_place<<<5000, 256, 0, stream>>>(eidx, row_start, rnk, perm);
    k_precompute<<<10000, 256, 0, stream>>>(scalars, Wa1, ba1, P1, P2);
    k_edges_sorted<<<5000, 256, 0, stream>>>(edge_vec, eidx, perm, P1, P2,
                                             tbl, b1, Wa2, ba2,
                                             attsh, srcbuf, (uint*)hbuf);
    k_gather<<<20000, 256, 0, stream>>>(scalars, vectors, W2, b2, row_start,
                                        attsh, srcbuf, (const uint*)hbuf, (float*)d_out);
}